// Round 12
// baseline (7558.604 us; speedup 1.0000x reference)
//
#include <hip/hip_runtime.h>

#define NN 50000
#define EE 800000
#define DIN 128
#define DH 64
#define CC 4
#define LL 3

typedef float f32x16 __attribute__((ext_vector_type(16)));

__device__ __forceinline__ float sigmoidf_(float x) {
    return __builtin_amdgcn_rcpf(1.0f + __expf(-x));
}

// DPP quad_perm broadcast/permute (VALU-only cross-lane within groups of 4)
#define QPERM(x, CTRL) (__int_as_float(__builtin_amdgcn_update_dpp(0, __float_as_int(x), (CTRL), 0xF, 0xF, true)))
#define QB0 0x00
#define QB1 0x55
#define QB2 0xAA
#define QB3 0xFF
#define QXOR1 0xB1   // [1,0,3,2]
#define QXOR2 0x4E   // [2,3,0,1]

#define LOAD16(V, P) { const float4* _p4 = (const float4*)(P); \
    float4 _a=_p4[0], _b=_p4[1], _c=_p4[2], _d=_p4[3]; \
    V[0]=_a.x; V[1]=_a.y; V[2]=_a.z; V[3]=_a.w; \
    V[4]=_b.x; V[5]=_b.y; V[6]=_b.z; V[7]=_b.w; \
    V[8]=_c.x; V[9]=_c.y; V[10]=_c.z; V[11]=_c.w; \
    V[12]=_d.x; V[13]=_d.y; V[14]=_d.z; V[15]=_d.w; }

#define ADD16(V, U) { \
    V[0]+=U[0];  V[1]+=U[1];  V[2]+=U[2];  V[3]+=U[3]; \
    V[4]+=U[4];  V[5]+=U[5];  V[6]+=U[6];  V[7]+=U[7]; \
    V[8]+=U[8];  V[9]+=U[9];  V[10]+=U[10]; V[11]+=U[11]; \
    V[12]+=U[12]; V[13]+=U[13]; V[14]+=U[14]; V[15]+=U[15]; }

#define FMAV(V, W, xv) { const float _xf = (xv); \
    V[0]+=_xf*W[0];  V[1]+=_xf*W[1];  V[2]+=_xf*W[2];  V[3]+=_xf*W[3]; \
    V[4]+=_xf*W[4];  V[5]+=_xf*W[5];  V[6]+=_xf*W[6];  V[7]+=_xf*W[7]; \
    V[8]+=_xf*W[8];  V[9]+=_xf*W[9];  V[10]+=_xf*W[10]; V[11]+=_xf*W[11]; \
    V[12]+=_xf*W[12]; V[13]+=_xf*W[13]; V[14]+=_xf*W[14]; V[15]+=_xf*W[15]; }

#define SILU16(V) { \
    V[0]*=sigmoidf_(V[0]);  V[1]*=sigmoidf_(V[1]);  V[2]*=sigmoidf_(V[2]);  V[3]*=sigmoidf_(V[3]); \
    V[4]*=sigmoidf_(V[4]);  V[5]*=sigmoidf_(V[5]);  V[6]*=sigmoidf_(V[6]);  V[7]*=sigmoidf_(V[7]); \
    V[8]*=sigmoidf_(V[8]);  V[9]*=sigmoidf_(V[9]);  V[10]*=sigmoidf_(V[10]); V[11]*=sigmoidf_(V[11]); \
    V[12]*=sigmoidf_(V[12]); V[13]*=sigmoidf_(V[13]); V[14]*=sigmoidf_(V[14]); V[15]*=sigmoidf_(V[15]); }

#define MUL16(V, s) { \
    V[0]*=(s); V[1]*=(s); V[2]*=(s); V[3]*=(s); V[4]*=(s); V[5]*=(s); V[6]*=(s); V[7]*=(s); \
    V[8]*=(s); V[9]*=(s); V[10]*=(s); V[11]*=(s); V[12]*=(s); V[13]*=(s); V[14]*=(s); V[15]*=(s); }

#define DOTV(acc, V, W) { acc += V[0]*W[0]+V[1]*W[1]+V[2]*W[2]+V[3]*W[3] \
    +V[4]*W[4]+V[5]*W[5]+V[6]*W[6]+V[7]*W[7]+V[8]*W[8]+V[9]*W[9]+V[10]*W[10] \
    +V[11]*W[11]+V[12]*W[12]+V[13]*W[13]+V[14]*W[14]+V[15]*W[15]; }

#define SHFL16D(D, Ssrc, SS) { \
    D[0]=__shfl_down(Ssrc[0],SS);  D[1]=__shfl_down(Ssrc[1],SS); \
    D[2]=__shfl_down(Ssrc[2],SS);  D[3]=__shfl_down(Ssrc[3],SS); \
    D[4]=__shfl_down(Ssrc[4],SS);  D[5]=__shfl_down(Ssrc[5],SS); \
    D[6]=__shfl_down(Ssrc[6],SS);  D[7]=__shfl_down(Ssrc[7],SS); \
    D[8]=__shfl_down(Ssrc[8],SS);  D[9]=__shfl_down(Ssrc[9],SS); \
    D[10]=__shfl_down(Ssrc[10],SS); D[11]=__shfl_down(Ssrc[11],SS); \
    D[12]=__shfl_down(Ssrc[12],SS); D[13]=__shfl_down(Ssrc[13],SS); \
    D[14]=__shfl_down(Ssrc[14],SS); D[15]=__shfl_down(Ssrc[15],SS); }

// W2/PW1 k-step: DPP-broadcast source element r from quad lane of phase
#define WBK(WSRC, KK, QB, S0,S1,S2,S3, D0,D1,D2,D3, RR) { f32x16 Wv; \
    LOAD16(Wv, (WSRC) + (size_t)(KK)*DH + ck*16) \
    { const float _m0=QPERM(S0[RR],QB), _m1=QPERM(S1[RR],QB), _m2=QPERM(S2[RR],QB), _m3=QPERM(S3[RR],QB); \
      FMAV(D0,Wv,_m0) FMAV(D1,Wv,_m1) FMAV(D2,Wv,_m2) FMAV(D3,Wv,_m3) } }

#define WBPHASE(WSRC, P4, QB, S0,S1,S2,S3, D0,D1,D2,D3) \
    WBK(WSRC,(P4)*16+0, QB,S0,S1,S2,S3,D0,D1,D2,D3,0)  WBK(WSRC,(P4)*16+1, QB,S0,S1,S2,S3,D0,D1,D2,D3,1)  \
    WBK(WSRC,(P4)*16+2, QB,S0,S1,S2,S3,D0,D1,D2,D3,2)  WBK(WSRC,(P4)*16+3, QB,S0,S1,S2,S3,D0,D1,D2,D3,3)  \
    WBK(WSRC,(P4)*16+4, QB,S0,S1,S2,S3,D0,D1,D2,D3,4)  WBK(WSRC,(P4)*16+5, QB,S0,S1,S2,S3,D0,D1,D2,D3,5)  \
    WBK(WSRC,(P4)*16+6, QB,S0,S1,S2,S3,D0,D1,D2,D3,6)  WBK(WSRC,(P4)*16+7, QB,S0,S1,S2,S3,D0,D1,D2,D3,7)  \
    WBK(WSRC,(P4)*16+8, QB,S0,S1,S2,S3,D0,D1,D2,D3,8)  WBK(WSRC,(P4)*16+9, QB,S0,S1,S2,S3,D0,D1,D2,D3,9)  \
    WBK(WSRC,(P4)*16+10,QB,S0,S1,S2,S3,D0,D1,D2,D3,10) WBK(WSRC,(P4)*16+11,QB,S0,S1,S2,S3,D0,D1,D2,D3,11) \
    WBK(WSRC,(P4)*16+12,QB,S0,S1,S2,S3,D0,D1,D2,D3,12) WBK(WSRC,(P4)*16+13,QB,S0,S1,S2,S3,D0,D1,D2,D3,13) \
    WBK(WSRC,(P4)*16+14,QB,S0,S1,S2,S3,D0,D1,D2,D3,14) WBK(WSRC,(P4)*16+15,QB,S0,S1,S2,S3,D0,D1,D2,D3,15)

// key-chain step (channel-independent scan multipliers)
#define KEYSTEP(SS, ADV) { \
    const int bhk = __shfl_down(hk, SS); const int btk = __shfl_down(tk, SS); \
    const float bfl = __shfl_down(fullf, SS); \
    const bool vq = (wl + SS) < 64; \
    const float mt = (vq && (tk == bhk)) ? 1.0f : 0.0f; \
    ADV = fullf * mt; \
    const float nf = fullf * bfl * mt; \
    fullf = vq ? nf : fullf; \
    tk = vq ? btk : tk; }

// payload scan step (per channel, precomputed multiplier)
#define PAYSTEP(SS, ADV) { \
    f32x16 bP; SHFL16D(bP, Pv, SS) \
    const float bpx=__shfl_down(ppx,SS), bpy=__shfl_down(ppy,SS), bpz=__shfl_down(ppz,SS); \
    FMAV(Pv, bP, ADV) ppx=fmaf(ADV,bpx,ppx); ppy=fmaf(ADV,bpy,ppy); ppz=fmaf(ADV,bpz,ppz); }

// gather hsp/hdp for channel CH into A0..A3 (A = hsp[s] + hdp[t])
#define GATHER(CH) { \
    const float* _hs = hsp + (size_t)(CH) * N * DH; \
    const float* _hd = hdp + (size_t)(CH) * N * DH; \
    f32x16 T; \
    LOAD16(A0, _hs + (size_t)s4.x * DH + ck*16) LOAD16(T, _hd + (size_t)t4.x * DH + ck*16) ADD16(A0, T) \
    LOAD16(A1, _hs + (size_t)s4.y * DH + ck*16) LOAD16(T, _hd + (size_t)t4.y * DH + ck*16) ADD16(A1, T) \
    LOAD16(A2, _hs + (size_t)s4.z * DH + ck*16) LOAD16(T, _hd + (size_t)t4.z * DH + ck*16) ADD16(A2, T) \
    LOAD16(A3, _hs + (size_t)s4.w * DH + ck*16) LOAD16(T, _hd + (size_t)t4.w * DH + ck*16) ADD16(A3, T) }

// ---------------- degree count ----------------
__global__ void cnt_kernel(const int* __restrict__ dst, int* __restrict__ cnt, int E) {
    int e = blockIdx.x * 256 + threadIdx.x;
    if (e < E) atomicAdd(&cnt[dst[e]], 1);
}

// ---------------- scans ----------------
__global__ __launch_bounds__(256) void scan1(const int* __restrict__ cnt, int* __restrict__ offs,
                                             int* __restrict__ bsum, int N) {
    __shared__ int sh[256];
    int i = blockIdx.x * 256 + threadIdx.x;
    int v = (i < N) ? cnt[i] : 0;
    sh[threadIdx.x] = v; __syncthreads();
    for (int s = 1; s < 256; s <<= 1) {
        int a = (threadIdx.x >= s) ? sh[threadIdx.x - s] : 0;
        __syncthreads(); sh[threadIdx.x] += a; __syncthreads();
    }
    int incl = sh[threadIdx.x];
    if (i < N) offs[i] = incl - v;
    if (threadIdx.x == 255) bsum[blockIdx.x] = incl;
}
__global__ __launch_bounds__(256) void scan2(int* __restrict__ bsum, int nb) {
    __shared__ int sh[256];
    int v = (threadIdx.x < nb) ? bsum[threadIdx.x] : 0;
    sh[threadIdx.x] = v; __syncthreads();
    for (int s = 1; s < 256; s <<= 1) {
        int a = (threadIdx.x >= s) ? sh[threadIdx.x - s] : 0;
        __syncthreads(); sh[threadIdx.x] += a; __syncthreads();
    }
    if (threadIdx.x < nb) bsum[threadIdx.x] = sh[threadIdx.x] - v;
}
__global__ void scan3(int* __restrict__ offs, const int* __restrict__ bsum, int N) {
    int i = blockIdx.x * 256 + threadIdx.x;
    if (i < N) offs[i] += bsum[blockIdx.x];
}

// ---------------- counting-sort by dst ----------------
__global__ void order_kernel(const int* __restrict__ src, const int* __restrict__ dst,
                             const int* __restrict__ offs, int* __restrict__ fill,
                             int* __restrict__ ssrc, int* __restrict__ sdst, int E) {
    int e = blockIdx.x * 256 + threadIdx.x;
    if (e < E) {
        int d = dst[e];
        int slot = offs[d] + atomicAdd(&fill[d], 1);
        ssrc[slot] = src[e];
        sdst[slot] = d;
    }
}

// ---------------- mix_in ----------------
__global__ __launch_bounds__(256) void mix_in_kernel(
        const float* __restrict__ x, const float* __restrict__ W,
        float* __restrict__ h, int N) {
    __shared__ float xs[8][DIN];
    const int i0 = blockIdx.x * 8;
    const int tid = threadIdx.x;
    for (int t = tid; t < 8 * DIN; t += 256) {
        int j = t / DIN, k = t % DIN;
        int i = i0 + j;
        xs[j][k] = (i < N) ? x[(size_t)i * DIN + k] : 0.f;
    }
    __syncthreads();
    float acc[8] = {0.f, 0.f, 0.f, 0.f, 0.f, 0.f, 0.f, 0.f};
    for (int k = 0; k < DIN; ++k) {
        float w = W[k * (CC * DH) + tid];
        #pragma unroll
        for (int j = 0; j < 8; ++j) acc[j] += xs[j][k] * w;
    }
    const int c = tid >> 6, d = tid & 63;
    #pragma unroll
    for (int j = 0; j < 8; ++j) {
        int i = i0 + j;
        if (i < N) h[((size_t)c * N + i) * DH + d] = acc[j];
    }
}

// ---------------- pre_kernel: hsp = h@W1s ; hdp = h@W1d + B1 ----------------
__global__ __launch_bounds__(256) void pre_kernel(
        const float* __restrict__ h, const float* __restrict__ ew1,
        const float* __restrict__ eb1,
        float* __restrict__ hsp, float* __restrict__ hdp, int N) {
    const int c = blockIdx.y;
    const int wave = threadIdx.x >> 6, lane = threadIdx.x & 63;
    const int i = blockIdx.x * 4 + wave;
    if (i >= N) return;
    const float* hrow = h + ((size_t)c * N + i) * DH;
    const float* W1 = ew1 + (size_t)c * (2 * DH + 1) * DH;
    float a_s = 0.f;
    float a_d = eb1[(size_t)c * DH + lane];
    #pragma unroll 8
    for (int k = 0; k < DH; ++k) {
        const float hv = hrow[k];
        a_s += hv * W1[(size_t)k * DH + lane];
        a_d += hv * W1[(size_t)(DH + k) * DH + lane];
    }
    hsp[((size_t)c * N + i) * DH + lane] = a_s;
    hdp[((size_t)c * N + i) * DH + lane] = a_d;
}

// ---------------- edge kernel: channel-merged quad decomposition ----------------
// One block: 256 edges x ALL 4 channels. Index/pos/scan-keys computed once;
// channel c+1's gathers issued during channel c's tail (latency hidden).
__global__ __launch_bounds__(256, 2) void edge_kernel(
    const float* __restrict__ hsp, const float* __restrict__ hdp,
    const float* __restrict__ pos,
    const int* __restrict__ ssrc, const int* __restrict__ sdst,
    const float* __restrict__ ew1,
    const float* __restrict__ ew2, const float* __restrict__ eb2,
    const float* __restrict__ gw,  const float* __restrict__ gb,
    const float* __restrict__ pw1, const float* __restrict__ pb1,
    const float* __restrict__ pw2,
    float* __restrict__ agg, float* __restrict__ pos_acc,
    int E, int N)
{
    __shared__ float sW2[DH * DH];             // 16 KB
    __shared__ float sPW1[DH * DH];            // 16 KB
    __shared__ float sB2[DH], sPB1[DH], sGW[DH], sPW2[DH];

    const int tid = threadIdx.x;
    const int wl   = tid & 63;
    const int ck   = wl & 3;
    const int quad = wl >> 2;
    const int qedge = blockIdx.x * 256 + (tid >> 6) * 64 + quad * 4;

    const int4 s4 = *(const int4*)(ssrc + qedge);
    const int4 t4 = *(const int4*)(sdst + qedge);
    const int d_0 = t4.x, d_1 = t4.y, d_2 = t4.z, d_3 = t4.w;

    // rel + d2 per edge (once)
    const float rx0 = pos[3*s4.x+0]-pos[3*t4.x+0], ry0 = pos[3*s4.x+1]-pos[3*t4.x+1], rz0 = pos[3*s4.x+2]-pos[3*t4.x+2];
    const float rx1 = pos[3*s4.y+0]-pos[3*t4.y+0], ry1 = pos[3*s4.y+1]-pos[3*t4.y+1], rz1 = pos[3*s4.y+2]-pos[3*t4.y+2];
    const float rx2 = pos[3*s4.z+0]-pos[3*t4.z+0], ry2 = pos[3*s4.z+1]-pos[3*t4.z+1], rz2 = pos[3*s4.z+2]-pos[3*t4.z+2];
    const float rx3 = pos[3*s4.w+0]-pos[3*t4.w+0], ry3 = pos[3*s4.w+1]-pos[3*t4.w+1], rz3 = pos[3*s4.w+2]-pos[3*t4.w+2];
    const float dd0 = rx0*rx0+ry0*ry0+rz0*rz0;
    const float dd1 = rx1*rx1+ry1*ry1+rz1*rz1;
    const float dd2 = rx2*rx2+ry2*ry2+rz2*rz2;
    const float dd3 = rx3*rx3+ry3*ry3+rz3*rz3;

    // run structure (once)
    const float e01 = (d_0 == d_1) ? 1.f : 0.f;
    const float e12 = (d_1 == d_2) ? 1.f : 0.f;
    const float e23 = (d_2 == d_3) ? 1.f : 0.f;
    const float full0 = e01 * e12 * e23;
    const float f1 = e12 * e23;
    const float f2 = e23;
    // key-chain multipliers (once)
    float fullf = full0;
    int tk = d_3;
    const int hk = d_0;
    float ad_1, ad_2, ad_3, ad_4;
    KEYSTEP(4, ad_1) KEYSTEP(8, ad_2) KEYSTEP(16, ad_3) KEYSTEP(32, ad_4)
    const int g1hk = __shfl_down(d_0, 4);
    const float sf = (((wl + 4) < 64) && (d_3 == g1hk)) ? 1.f : 0.f;
    const int pd = __shfl_up(d_3, 4);
    const bool h0 = (quad == 0) || (pd != d_0);
    const bool h1 = (e01 == 0.f);
    const bool h2 = (e12 == 0.f);
    const bool h3 = (e23 == 0.f);

    // prefetch channel-0 gathers
    f32x16 A0, A1, A2, A3;
    GATHER(0)

    #pragma unroll 1
    for (int ch = 0; ch < CC; ++ch) {
        __syncthreads();   // previous channel's LDS reads complete
        // ---- stage W2, PW1 + vectors for this channel ----
        {
            const float4* g2 = (const float4*)(ew2 + (size_t)ch * DH * DH);
            float4* l2 = (float4*)sW2;
            #pragma unroll
            for (int i = 0; i < 4; ++i) l2[tid + i * 256] = g2[tid + i * 256];
            const float4* g3 = (const float4*)(pw1 + (size_t)ch * DH * DH);
            float4* l3 = (float4*)sPW1;
            #pragma unroll
            for (int i = 0; i < 4; ++i) l3[tid + i * 256] = g3[tid + i * 256];
            if (tid < DH) {
                sB2[tid]  = eb2[(size_t)ch * DH + tid];
                sPB1[tid] = pb1[(size_t)ch * DH + tid];
                sGW[tid]  = gw[(size_t)ch * DH + tid];
                sPW2[tid] = pw2[(size_t)ch * DH + tid];
            }
        }
        f32x16 W128v;
        LOAD16(W128v, ew1 + (size_t)ch * (2 * DH + 1) * DH + (size_t)(2 * DH) * DH + ck * 16)
        const float GB = gb[ch];
        __syncthreads();

        // ---- m1 = silu(A + d2*w128) ----  (A = hsp[s]+hdp[t], pre-gathered)
        FMAV(A0, W128v, dd0) FMAV(A1, W128v, dd1) FMAV(A2, W128v, dd2) FMAV(A3, W128v, dd3)
        SILU16(A0) SILU16(A1) SILU16(A2) SILU16(A3)

        // ---- m2 = silu(m1 @ W2 + B2) ----
        f32x16 B0v, B1v, B2v, B3v;
        { f32x16 bz; LOAD16(bz, sB2 + ck*16) B0v = bz; B1v = bz; B2v = bz; B3v = bz; }
        WBPHASE(sW2, 0, QB0, A0,A1,A2,A3, B0v,B1v,B2v,B3v)
        WBPHASE(sW2, 1, QB1, A0,A1,A2,A3, B0v,B1v,B2v,B3v)
        WBPHASE(sW2, 2, QB2, A0,A1,A2,A3, B0v,B1v,B2v,B3v)
        WBPHASE(sW2, 3, QB3, A0,A1,A2,A3, B0v,B1v,B2v,B3v)
        SILU16(B0v) SILU16(B1v) SILU16(B2v) SILU16(B3v)

        // ---- gate ----
        {
            f32x16 GWv; LOAD16(GWv, sGW + ck*16)
            float g0 = 0.f, g1 = 0.f, g2 = 0.f, g3 = 0.f;
            DOTV(g0, B0v, GWv) DOTV(g1, B1v, GWv) DOTV(g2, B2v, GWv) DOTV(g3, B3v, GWv)
            g0 += QPERM(g0, QXOR1); g0 += QPERM(g0, QXOR2);
            g1 += QPERM(g1, QXOR1); g1 += QPERM(g1, QXOR2);
            g2 += QPERM(g2, QXOR1); g2 += QPERM(g2, QXOR2);
            g3 += QPERM(g3, QXOR1); g3 += QPERM(g3, QXOR2);
            const float ga0 = sigmoidf_(GB + g0), ga1 = sigmoidf_(GB + g1);
            const float ga2 = sigmoidf_(GB + g2), ga3 = sigmoidf_(GB + g3);
            MUL16(B0v, ga0) MUL16(B1v, ga1) MUL16(B2v, ga2) MUL16(B3v, ga3)
        }

        // ---- q = silu(m @ PW1 + PB1); p = q @ PW2 ----  (q reuses A)
        { f32x16 bz; LOAD16(bz, sPB1 + ck*16) A0 = bz; A1 = bz; A2 = bz; A3 = bz; }
        WBPHASE(sPW1, 0, QB0, B0v,B1v,B2v,B3v, A0,A1,A2,A3)
        WBPHASE(sPW1, 1, QB1, B0v,B1v,B2v,B3v, A0,A1,A2,A3)
        WBPHASE(sPW1, 2, QB2, B0v,B1v,B2v,B3v, A0,A1,A2,A3)
        WBPHASE(sPW1, 3, QB3, B0v,B1v,B2v,B3v, A0,A1,A2,A3)
        SILU16(A0) SILU16(A1) SILU16(A2) SILU16(A3)
        float p0 = 0.f, p1 = 0.f, p2 = 0.f, p3 = 0.f;
        {
            f32x16 PW2v; LOAD16(PW2v, sPW2 + ck*16)
            DOTV(p0, A0, PW2v) DOTV(p1, A1, PW2v) DOTV(p2, A2, PW2v) DOTV(p3, A3, PW2v)
            p0 += QPERM(p0, QXOR1); p0 += QPERM(p0, QXOR2);
            p1 += QPERM(p1, QXOR1); p1 += QPERM(p1, QXOR2);
            p2 += QPERM(p2, QXOR1); p2 += QPERM(p2, QXOR2);
            p3 += QPERM(p3, QXOR1); p3 += QPERM(p3, QXOR2);
        }

        // A free now: prefetch next channel's gathers (hidden under scan+flush+staging)
        if (ch < CC - 1) { GATHER(ch + 1) }

        float tx0 = fminf(fmaxf(rx0*p0, -2.f), 2.f), ty0 = fminf(fmaxf(ry0*p0, -2.f), 2.f), tz0 = fminf(fmaxf(rz0*p0, -2.f), 2.f);
        float tx1 = fminf(fmaxf(rx1*p1, -2.f), 2.f), ty1 = fminf(fmaxf(ry1*p1, -2.f), 2.f), tz1 = fminf(fmaxf(rz1*p1, -2.f), 2.f);
        float tx2 = fminf(fmaxf(rx2*p2, -2.f), 2.f), ty2 = fminf(fmaxf(ry2*p2, -2.f), 2.f), tz2 = fminf(fmaxf(rz2*p2, -2.f), 2.f);
        float tx3 = fminf(fmaxf(rx3*p3, -2.f), 2.f), ty3 = fminf(fmaxf(ry3*p3, -2.f), 2.f), tz3 = fminf(fmaxf(rz3*p3, -2.f), 2.f);

        // ---- in-lane suffix merge ----
        FMAV(B2v, B3v, e23) tx2 = fmaf(e23, tx3, tx2); ty2 = fmaf(e23, ty3, ty2); tz2 = fmaf(e23, tz3, tz2);
        FMAV(B1v, B2v, e12) tx1 = fmaf(e12, tx2, tx1); ty1 = fmaf(e12, ty2, ty1); tz1 = fmaf(e12, tz2, tz1);
        FMAV(B0v, B1v, e01) tx0 = fmaf(e01, tx1, tx0); ty0 = fmaf(e01, ty1, ty0); tz0 = fmaf(e01, tz1, tz0);

        // ---- cross-quad payload scan (keys precomputed) ----
        f32x16 Pv = B0v;
        float ppx = tx0, ppy = ty0, ppz = tz0;
        PAYSTEP(4, ad_1) PAYSTEP(8, ad_2) PAYSTEP(16, ad_3) PAYSTEP(32, ad_4)
        f32x16 Sv; SHFL16D(Sv, Pv, 4)
        float spx = __shfl_down(ppx, 4), spy = __shfl_down(ppy, 4), spz = __shfl_down(ppz, 4);
        MUL16(Sv, sf) spx *= sf; spy *= sf; spz *= sf;

#define FLUSH(COND, DJ, BV, F, TX, TY, TZ) \
        if (COND) { \
            float* ar = agg + ((size_t)ch * N + (DJ)) * DH + ck * 16; \
            atomicAdd(ar+0,  BV[0]+(F)*Sv[0]);   atomicAdd(ar+1,  BV[1]+(F)*Sv[1]); \
            atomicAdd(ar+2,  BV[2]+(F)*Sv[2]);   atomicAdd(ar+3,  BV[3]+(F)*Sv[3]); \
            atomicAdd(ar+4,  BV[4]+(F)*Sv[4]);   atomicAdd(ar+5,  BV[5]+(F)*Sv[5]); \
            atomicAdd(ar+6,  BV[6]+(F)*Sv[6]);   atomicAdd(ar+7,  BV[7]+(F)*Sv[7]); \
            atomicAdd(ar+8,  BV[8]+(F)*Sv[8]);   atomicAdd(ar+9,  BV[9]+(F)*Sv[9]); \
            atomicAdd(ar+10, BV[10]+(F)*Sv[10]); atomicAdd(ar+11, BV[11]+(F)*Sv[11]); \
            atomicAdd(ar+12, BV[12]+(F)*Sv[12]); atomicAdd(ar+13, BV[13]+(F)*Sv[13]); \
            atomicAdd(ar+14, BV[14]+(F)*Sv[14]); atomicAdd(ar+15, BV[15]+(F)*Sv[15]); \
            if (ck == 0) { \
                atomicAdd(&pos_acc[(DJ)*3+0], (TX)+(F)*spx); \
                atomicAdd(&pos_acc[(DJ)*3+1], (TY)+(F)*spy); \
                atomicAdd(&pos_acc[(DJ)*3+2], (TZ)+(F)*spz); } }

        FLUSH(h0, d_0, B0v, full0, tx0, ty0, tz0)
        FLUSH(h1, d_1, B1v, f1,    tx1, ty1, tz1)
        FLUSH(h2, d_2, B2v, f2,    tx2, ty2, tz2)
        FLUSH(h3, d_3, B3v, 1.0f,  tx3, ty3, tz3)
#undef FLUSH
    }
}

// ---------------- node update ----------------
__global__ __launch_bounds__(256) void node_kernel(
        const float* __restrict__ h, float* __restrict__ agg,
        const float* __restrict__ nw, const float* __restrict__ nb, int N) {
    const int c = blockIdx.y;
    const int wave = threadIdx.x >> 6, lane = threadIdx.x & 63;
    const int i = blockIdx.x * 4 + wave;
    if (i >= N) return;
    const float* hrow = h + ((size_t)c * N + i) * DH;
    float* arow = agg + ((size_t)c * N + i) * DH;
    const float* W = nw + (size_t)c * (2 * DH) * DH;
    float acc = nb[(size_t)c * DH + lane];
    #pragma unroll 8
    for (int k = 0; k < DH; ++k) acc += hrow[k] * W[(size_t)k * DH + lane];
    #pragma unroll 8
    for (int k = 0; k < DH; ++k) acc += arow[k] * W[(size_t)(DH + k) * DH + lane];
    arow[lane] = acc;
}

// ---------------- mix_out ----------------
__global__ __launch_bounds__(256) void mix_out_kernel(
        const float* __restrict__ hout, const float* __restrict__ W,
        float* __restrict__ x, int N) {
    __shared__ float hs[8][CC * DH];
    const int i0 = blockIdx.x * 8;
    const int tid = threadIdx.x;
    for (int t = tid; t < 8 * CC * DH; t += 256) {
        int j = t >> 8, cd = t & 255;
        int c = cd >> 6, d = cd & 63;
        int i = i0 + j;
        hs[j][cd] = (i < N) ? hout[((size_t)c * N + i) * DH + d] : 0.f;
    }
    __syncthreads();
    const int o = tid & 127, g = tid >> 7;
    float acc[4] = {0.f, 0.f, 0.f, 0.f};
    for (int cd = 0; cd < CC * DH; ++cd) {
        float w = W[(size_t)cd * DIN + o];
        #pragma unroll
        for (int j = 0; j < 4; ++j) acc[j] += hs[g * 4 + j][cd] * w;
    }
    #pragma unroll
    for (int j = 0; j < 4; ++j) {
        int i = i0 + g * 4 + j;
        if (i < N) x[(size_t)i * DIN + o] += acc[j];
    }
}

// ---------------- pos finalize ----------------
__global__ void pos_fin_kernel(float* __restrict__ pos, const float* __restrict__ pos_acc,
                               const int* __restrict__ cnt, int N) {
    int i = blockIdx.x * 256 + threadIdx.x;
    if (i < N) {
        float inv = 1.0f / ((float)CC * fmaxf((float)cnt[i], 1.0f));
        pos[i * 3 + 0] += pos_acc[i * 3 + 0] * inv;
        pos[i * 3 + 1] += pos_acc[i * 3 + 1] * inv;
        pos[i * 3 + 2] += pos_acc[i * 3 + 2] * inv;
    }
}

extern "C" void kernel_launch(void* const* d_in, const int* in_sizes, int n_in,
                              void* d_out, int out_size, void* d_ws, size_t ws_size,
                              hipStream_t stream) {
    const float* x         = (const float*)d_in[0];
    const float* pos       = (const float*)d_in[1];
    const int*   ei        = (const int*)d_in[2];
    const float* mix_in_w  = (const float*)d_in[3];
    const float* mix_out_w = (const float*)d_in[4];
    const float* ew1       = (const float*)d_in[5];
    const float* eb1       = (const float*)d_in[6];
    const float* ew2       = (const float*)d_in[7];
    const float* eb2       = (const float*)d_in[8];
    const float* gw        = (const float*)d_in[9];
    const float* gb        = (const float*)d_in[10];
    const float* nw        = (const float*)d_in[11];
    const float* nb        = (const float*)d_in[12];
    const float* pw1       = (const float*)d_in[13];
    const float* pb1       = (const float*)d_in[14];
    const float* pw2       = (const float*)d_in[15];

    const int* src = ei;
    const int* dst = ei + EE;

    float* xout    = (float*)d_out;
    float* pos_out = xout + (size_t)NN * DIN;

    float* hbuf    = (float*)d_ws;                     // C*N*64
    float* aggb    = hbuf + (size_t)CC * NN * DH;      // C*N*64
    float* hsp     = aggb + (size_t)CC * NN * DH;      // C*N*64
    float* hdp     = hsp  + (size_t)CC * NN * DH;      // C*N*64
    float* pos_cur = hdp  + (size_t)CC * NN * DH;      // N*3
    float* pos_acc = pos_cur + (size_t)NN * 3;         // N*3
    int*   cnt_i   = (int*)(pos_acc + (size_t)NN * 3); // N
    int*   offs    = cnt_i + NN;                       // N
    int*   fill    = offs + NN;                        // N
    int*   bsum    = fill + NN;                        // 256
    int*   ssrc    = bsum + 256;                       // E
    int*   sdst    = ssrc + EE;                        // E

    const int NB = (NN + 255) / 256;

    hipMemcpyAsync(xout, x, sizeof(float) * NN * DIN, hipMemcpyDeviceToDevice, stream);
    hipMemcpyAsync(pos_cur, pos, sizeof(float) * NN * 3, hipMemcpyDeviceToDevice, stream);
    hipMemsetAsync(cnt_i, 0, sizeof(int) * NN, stream);
    hipMemsetAsync(fill, 0, sizeof(int) * NN, stream);

    cnt_kernel<<<(EE + 255) / 256, 256, 0, stream>>>(dst, cnt_i, EE);
    scan1<<<NB, 256, 0, stream>>>(cnt_i, offs, bsum, NN);
    scan2<<<1, 256, 0, stream>>>(bsum, NB);
    scan3<<<NB, 256, 0, stream>>>(offs, bsum, NN);
    order_kernel<<<(EE + 255) / 256, 256, 0, stream>>>(src, dst, offs, fill, ssrc, sdst, EE);

    for (int l = 0; l < LL; ++l) {
        hipMemsetAsync(aggb, 0, sizeof(float) * CC * NN * DH, stream);
        hipMemsetAsync(pos_acc, 0, sizeof(float) * NN * 3, stream);

        mix_in_kernel<<<(NN + 7) / 8, 256, 0, stream>>>(
            xout, mix_in_w + (size_t)l * DIN * CC * DH, hbuf, NN);

        pre_kernel<<<dim3((NN + 3) / 4, CC), 256, 0, stream>>>(
            hbuf,
            ew1 + (size_t)l * CC * (2 * DH + 1) * DH,
            eb1 + (size_t)l * CC * DH,
            hsp, hdp, NN);

        edge_kernel<<<EE / 256, 256, 0, stream>>>(
            hsp, hdp, pos_cur, ssrc, sdst,
            ew1 + (size_t)l * CC * (2 * DH + 1) * DH,
            ew2 + (size_t)l * CC * DH * DH,
            eb2 + (size_t)l * CC * DH,
            gw  + (size_t)l * CC * DH,
            gb  + (size_t)l * CC,
            pw1 + (size_t)l * CC * DH * DH,
            pb1 + (size_t)l * CC * DH,
            pw2 + (size_t)l * CC * DH,
            aggb, pos_acc, EE, NN);

        node_kernel<<<dim3((NN + 3) / 4, CC), 256, 0, stream>>>(
            hbuf, aggb,
            nw + (size_t)l * CC * 2 * DH * DH,
            nb + (size_t)l * CC * DH, NN);

        mix_out_kernel<<<(NN + 7) / 8, 256, 0, stream>>>(
            aggb, mix_out_w + (size_t)l * CC * DH * DIN, xout, NN);

        pos_fin_kernel<<<(NN + 255) / 256, 256, 0, stream>>>(pos_cur, pos_acc, cnt_i, NN);
    }

    hipMemcpyAsync(pos_out, pos_cur, sizeof(float) * NN * 3, hipMemcpyDeviceToDevice, stream);
}

// Round 13
// 7524.322 us; speedup vs baseline: 1.0046x; 1.0046x over previous
//
#include <hip/hip_runtime.h>

#define NN 50000
#define EE 800000
#define DIN 128
#define DH 64
#define CC 4
#define LL 3

typedef float f32x16 __attribute__((ext_vector_type(16)));

__device__ __forceinline__ float sigmoidf_(float x) {
    return __builtin_amdgcn_rcpf(1.0f + __expf(-x));
}

// DPP quad_perm broadcast/permute (VALU-only cross-lane within groups of 4)
#define QPERM(x, CTRL) (__int_as_float(__builtin_amdgcn_update_dpp(0, __float_as_int(x), (CTRL), 0xF, 0xF, true)))
#define QB0 0x00
#define QB1 0x55
#define QB2 0xAA
#define QB3 0xFF
#define QXOR1 0xB1   // [1,0,3,2]
#define QXOR2 0x4E   // [2,3,0,1]

#define LOAD16(V, P) { const float4* _p4 = (const float4*)(P); \
    float4 _a=_p4[0], _b=_p4[1], _c=_p4[2], _d=_p4[3]; \
    V[0]=_a.x; V[1]=_a.y; V[2]=_a.z; V[3]=_a.w; \
    V[4]=_b.x; V[5]=_b.y; V[6]=_b.z; V[7]=_b.w; \
    V[8]=_c.x; V[9]=_c.y; V[10]=_c.z; V[11]=_c.w; \
    V[12]=_d.x; V[13]=_d.y; V[14]=_d.z; V[15]=_d.w; }

#define ADD16(V, U) { \
    V[0]+=U[0];  V[1]+=U[1];  V[2]+=U[2];  V[3]+=U[3]; \
    V[4]+=U[4];  V[5]+=U[5];  V[6]+=U[6];  V[7]+=U[7]; \
    V[8]+=U[8];  V[9]+=U[9];  V[10]+=U[10]; V[11]+=U[11]; \
    V[12]+=U[12]; V[13]+=U[13]; V[14]+=U[14]; V[15]+=U[15]; }

#define FMAV(V, W, xv) { const float _xf = (xv); \
    V[0]+=_xf*W[0];  V[1]+=_xf*W[1];  V[2]+=_xf*W[2];  V[3]+=_xf*W[3]; \
    V[4]+=_xf*W[4];  V[5]+=_xf*W[5];  V[6]+=_xf*W[6];  V[7]+=_xf*W[7]; \
    V[8]+=_xf*W[8];  V[9]+=_xf*W[9];  V[10]+=_xf*W[10]; V[11]+=_xf*W[11]; \
    V[12]+=_xf*W[12]; V[13]+=_xf*W[13]; V[14]+=_xf*W[14]; V[15]+=_xf*W[15]; }

#define SILU16(V) { \
    V[0]*=sigmoidf_(V[0]);  V[1]*=sigmoidf_(V[1]);  V[2]*=sigmoidf_(V[2]);  V[3]*=sigmoidf_(V[3]); \
    V[4]*=sigmoidf_(V[4]);  V[5]*=sigmoidf_(V[5]);  V[6]*=sigmoidf_(V[6]);  V[7]*=sigmoidf_(V[7]); \
    V[8]*=sigmoidf_(V[8]);  V[9]*=sigmoidf_(V[9]);  V[10]*=sigmoidf_(V[10]); V[11]*=sigmoidf_(V[11]); \
    V[12]*=sigmoidf_(V[12]); V[13]*=sigmoidf_(V[13]); V[14]*=sigmoidf_(V[14]); V[15]*=sigmoidf_(V[15]); }

#define MUL16(V, s) { \
    V[0]*=(s); V[1]*=(s); V[2]*=(s); V[3]*=(s); V[4]*=(s); V[5]*=(s); V[6]*=(s); V[7]*=(s); \
    V[8]*=(s); V[9]*=(s); V[10]*=(s); V[11]*=(s); V[12]*=(s); V[13]*=(s); V[14]*=(s); V[15]*=(s); }

#define DOTV(acc, V, W) { acc += V[0]*W[0]+V[1]*W[1]+V[2]*W[2]+V[3]*W[3] \
    +V[4]*W[4]+V[5]*W[5]+V[6]*W[6]+V[7]*W[7]+V[8]*W[8]+V[9]*W[9]+V[10]*W[10] \
    +V[11]*W[11]+V[12]*W[12]+V[13]*W[13]+V[14]*W[14]+V[15]*W[15]; }

#define SHFL16D(D, Ssrc, SS) { \
    D[0]=__shfl_down(Ssrc[0],SS);  D[1]=__shfl_down(Ssrc[1],SS); \
    D[2]=__shfl_down(Ssrc[2],SS);  D[3]=__shfl_down(Ssrc[3],SS); \
    D[4]=__shfl_down(Ssrc[4],SS);  D[5]=__shfl_down(Ssrc[5],SS); \
    D[6]=__shfl_down(Ssrc[6],SS);  D[7]=__shfl_down(Ssrc[7],SS); \
    D[8]=__shfl_down(Ssrc[8],SS);  D[9]=__shfl_down(Ssrc[9],SS); \
    D[10]=__shfl_down(Ssrc[10],SS); D[11]=__shfl_down(Ssrc[11],SS); \
    D[12]=__shfl_down(Ssrc[12],SS); D[13]=__shfl_down(Ssrc[13],SS); \
    D[14]=__shfl_down(Ssrc[14],SS); D[15]=__shfl_down(Ssrc[15],SS); }

// W2/PW1 k-step: DPP-broadcast source element r from quad lane of phase
#define WBK(WSRC, KK, QB, S0,S1,S2,S3, D0,D1,D2,D3, RR) { f32x16 Wv; \
    LOAD16(Wv, (WSRC) + (size_t)(KK)*DH + ck*16) \
    { const float _m0=QPERM(S0[RR],QB), _m1=QPERM(S1[RR],QB), _m2=QPERM(S2[RR],QB), _m3=QPERM(S3[RR],QB); \
      FMAV(D0,Wv,_m0) FMAV(D1,Wv,_m1) FMAV(D2,Wv,_m2) FMAV(D3,Wv,_m3) } }

#define WBPHASE(WSRC, P4, QB, S0,S1,S2,S3, D0,D1,D2,D3) \
    WBK(WSRC,(P4)*16+0, QB,S0,S1,S2,S3,D0,D1,D2,D3,0)  WBK(WSRC,(P4)*16+1, QB,S0,S1,S2,S3,D0,D1,D2,D3,1)  \
    WBK(WSRC,(P4)*16+2, QB,S0,S1,S2,S3,D0,D1,D2,D3,2)  WBK(WSRC,(P4)*16+3, QB,S0,S1,S2,S3,D0,D1,D2,D3,3)  \
    WBK(WSRC,(P4)*16+4, QB,S0,S1,S2,S3,D0,D1,D2,D3,4)  WBK(WSRC,(P4)*16+5, QB,S0,S1,S2,S3,D0,D1,D2,D3,5)  \
    WBK(WSRC,(P4)*16+6, QB,S0,S1,S2,S3,D0,D1,D2,D3,6)  WBK(WSRC,(P4)*16+7, QB,S0,S1,S2,S3,D0,D1,D2,D3,7)  \
    WBK(WSRC,(P4)*16+8, QB,S0,S1,S2,S3,D0,D1,D2,D3,8)  WBK(WSRC,(P4)*16+9, QB,S0,S1,S2,S3,D0,D1,D2,D3,9)  \
    WBK(WSRC,(P4)*16+10,QB,S0,S1,S2,S3,D0,D1,D2,D3,10) WBK(WSRC,(P4)*16+11,QB,S0,S1,S2,S3,D0,D1,D2,D3,11) \
    WBK(WSRC,(P4)*16+12,QB,S0,S1,S2,S3,D0,D1,D2,D3,12) WBK(WSRC,(P4)*16+13,QB,S0,S1,S2,S3,D0,D1,D2,D3,13) \
    WBK(WSRC,(P4)*16+14,QB,S0,S1,S2,S3,D0,D1,D2,D3,14) WBK(WSRC,(P4)*16+15,QB,S0,S1,S2,S3,D0,D1,D2,D3,15)

// key-chain step (channel-independent scan multipliers)
#define KEYSTEP(SS, ADV) { \
    const int bhk = __shfl_down(hk, SS); const int btk = __shfl_down(tk, SS); \
    const float bfl = __shfl_down(fullf, SS); \
    const bool vq = (wl + SS) < 64; \
    const float mt = (vq && (tk == bhk)) ? 1.0f : 0.0f; \
    ADV = fullf * mt; \
    const float nf = fullf * bfl * mt; \
    fullf = vq ? nf : fullf; \
    tk = vq ? btk : tk; }

// payload scan step (per channel, precomputed multiplier)
#define PAYSTEP(SS, ADV) { \
    f32x16 bP; SHFL16D(bP, Pv, SS) \
    const float bpx=__shfl_down(ppx,SS), bpy=__shfl_down(ppy,SS), bpz=__shfl_down(ppz,SS); \
    FMAV(Pv, bP, ADV) ppx=fmaf(ADV,bpx,ppx); ppy=fmaf(ADV,bpy,ppy); ppz=fmaf(ADV,bpz,ppz); }

// gather hsp/hdp for channel CH into A0..A3 (A = hsp[s] + hdp[t])
// node-interleaved layout: hsp[(n*CC + CH)*DH + d] — all channels of a node contiguous (1 KB)
#define GATHER(CH) { \
    f32x16 T; \
    LOAD16(A0, hsp + ((size_t)s4.x * CC + (CH)) * DH + ck*16) \
    LOAD16(T,  hdp + ((size_t)t4.x * CC + (CH)) * DH + ck*16) ADD16(A0, T) \
    LOAD16(A1, hsp + ((size_t)s4.y * CC + (CH)) * DH + ck*16) \
    LOAD16(T,  hdp + ((size_t)t4.y * CC + (CH)) * DH + ck*16) ADD16(A1, T) \
    LOAD16(A2, hsp + ((size_t)s4.z * CC + (CH)) * DH + ck*16) \
    LOAD16(T,  hdp + ((size_t)t4.z * CC + (CH)) * DH + ck*16) ADD16(A2, T) \
    LOAD16(A3, hsp + ((size_t)s4.w * CC + (CH)) * DH + ck*16) \
    LOAD16(T,  hdp + ((size_t)t4.w * CC + (CH)) * DH + ck*16) ADD16(A3, T) }

// ---------------- degree count ----------------
__global__ void cnt_kernel(const int* __restrict__ dst, int* __restrict__ cnt, int E) {
    int e = blockIdx.x * 256 + threadIdx.x;
    if (e < E) atomicAdd(&cnt[dst[e]], 1);
}

// ---------------- scans ----------------
__global__ __launch_bounds__(256) void scan1(const int* __restrict__ cnt, int* __restrict__ offs,
                                             int* __restrict__ bsum, int N) {
    __shared__ int sh[256];
    int i = blockIdx.x * 256 + threadIdx.x;
    int v = (i < N) ? cnt[i] : 0;
    sh[threadIdx.x] = v; __syncthreads();
    for (int s = 1; s < 256; s <<= 1) {
        int a = (threadIdx.x >= s) ? sh[threadIdx.x - s] : 0;
        __syncthreads(); sh[threadIdx.x] += a; __syncthreads();
    }
    int incl = sh[threadIdx.x];
    if (i < N) offs[i] = incl - v;
    if (threadIdx.x == 255) bsum[blockIdx.x] = incl;
}
__global__ __launch_bounds__(256) void scan2(int* __restrict__ bsum, int nb) {
    __shared__ int sh[256];
    int v = (threadIdx.x < nb) ? bsum[threadIdx.x] : 0;
    sh[threadIdx.x] = v; __syncthreads();
    for (int s = 1; s < 256; s <<= 1) {
        int a = (threadIdx.x >= s) ? sh[threadIdx.x - s] : 0;
        __syncthreads(); sh[threadIdx.x] += a; __syncthreads();
    }
    if (threadIdx.x < nb) bsum[threadIdx.x] = sh[threadIdx.x] - v;
}
__global__ void scan3(int* __restrict__ offs, const int* __restrict__ bsum, int N) {
    int i = blockIdx.x * 256 + threadIdx.x;
    if (i < N) offs[i] += bsum[blockIdx.x];
}

// ---------------- counting-sort by dst ----------------
__global__ void order_kernel(const int* __restrict__ src, const int* __restrict__ dst,
                             const int* __restrict__ offs, int* __restrict__ fill,
                             int* __restrict__ ssrc, int* __restrict__ sdst, int E) {
    int e = blockIdx.x * 256 + threadIdx.x;
    if (e < E) {
        int d = dst[e];
        int slot = offs[d] + atomicAdd(&fill[d], 1);
        ssrc[slot] = src[e];
        sdst[slot] = d;
    }
}

// ---------------- mix_in ----------------
__global__ __launch_bounds__(256) void mix_in_kernel(
        const float* __restrict__ x, const float* __restrict__ W,
        float* __restrict__ h, int N) {
    __shared__ float xs[8][DIN];
    const int i0 = blockIdx.x * 8;
    const int tid = threadIdx.x;
    for (int t = tid; t < 8 * DIN; t += 256) {
        int j = t / DIN, k = t % DIN;
        int i = i0 + j;
        xs[j][k] = (i < N) ? x[(size_t)i * DIN + k] : 0.f;
    }
    __syncthreads();
    float acc[8] = {0.f, 0.f, 0.f, 0.f, 0.f, 0.f, 0.f, 0.f};
    for (int k = 0; k < DIN; ++k) {
        float w = W[k * (CC * DH) + tid];
        #pragma unroll
        for (int j = 0; j < 8; ++j) acc[j] += xs[j][k] * w;
    }
    const int c = tid >> 6, d = tid & 63;
    #pragma unroll
    for (int j = 0; j < 8; ++j) {
        int i = i0 + j;
        if (i < N) h[((size_t)c * N + i) * DH + d] = acc[j];
    }
}

// ---------------- pre_kernel: hsp[n][c] = h@W1s ; hdp[n][c] = h@W1d + B1 ----------------
__global__ __launch_bounds__(256) void pre_kernel(
        const float* __restrict__ h, const float* __restrict__ ew1,
        const float* __restrict__ eb1,
        float* __restrict__ hsp, float* __restrict__ hdp, int N) {
    const int c = blockIdx.y;
    const int wave = threadIdx.x >> 6, lane = threadIdx.x & 63;
    const int i = blockIdx.x * 4 + wave;
    if (i >= N) return;
    const float* hrow = h + ((size_t)c * N + i) * DH;
    const float* W1 = ew1 + (size_t)c * (2 * DH + 1) * DH;
    float a_s = 0.f;
    float a_d = eb1[(size_t)c * DH + lane];
    #pragma unroll 8
    for (int k = 0; k < DH; ++k) {
        const float hv = hrow[k];
        a_s += hv * W1[(size_t)k * DH + lane];
        a_d += hv * W1[(size_t)(DH + k) * DH + lane];
    }
    hsp[((size_t)i * CC + c) * DH + lane] = a_s;
    hdp[((size_t)i * CC + c) * DH + lane] = a_d;
}

// ---------------- edge kernel: channel-merged, node-interleaved gathers ----------------
__global__ __launch_bounds__(256, 2) void edge_kernel(
    const float* __restrict__ hsp, const float* __restrict__ hdp,
    const float* __restrict__ pos,
    const int* __restrict__ ssrc, const int* __restrict__ sdst,
    const float* __restrict__ ew1,
    const float* __restrict__ ew2, const float* __restrict__ eb2,
    const float* __restrict__ gw,  const float* __restrict__ gb,
    const float* __restrict__ pw1, const float* __restrict__ pb1,
    const float* __restrict__ pw2,
    float* __restrict__ agg, float* __restrict__ pos_acc,
    int E, int N)
{
    __shared__ float sW2[DH * DH];             // 16 KB
    __shared__ float sPW1[DH * DH];            // 16 KB
    __shared__ float sB2[DH], sPB1[DH], sGW[DH], sPW2[DH];

    const int tid = threadIdx.x;
    const int wl   = tid & 63;
    const int ck   = wl & 3;
    const int quad = wl >> 2;
    const int qedge = blockIdx.x * 256 + (tid >> 6) * 64 + quad * 4;

    const int4 s4 = *(const int4*)(ssrc + qedge);
    const int4 t4 = *(const int4*)(sdst + qedge);
    const int d_0 = t4.x, d_1 = t4.y, d_2 = t4.z, d_3 = t4.w;

    // rel + d2 per edge (once)
    const float rx0 = pos[3*s4.x+0]-pos[3*t4.x+0], ry0 = pos[3*s4.x+1]-pos[3*t4.x+1], rz0 = pos[3*s4.x+2]-pos[3*t4.x+2];
    const float rx1 = pos[3*s4.y+0]-pos[3*t4.y+0], ry1 = pos[3*s4.y+1]-pos[3*t4.y+1], rz1 = pos[3*s4.y+2]-pos[3*t4.y+2];
    const float rx2 = pos[3*s4.z+0]-pos[3*t4.z+0], ry2 = pos[3*s4.z+1]-pos[3*t4.z+1], rz2 = pos[3*s4.z+2]-pos[3*t4.z+2];
    const float rx3 = pos[3*s4.w+0]-pos[3*t4.w+0], ry3 = pos[3*s4.w+1]-pos[3*t4.w+1], rz3 = pos[3*s4.w+2]-pos[3*t4.w+2];
    const float dd0 = rx0*rx0+ry0*ry0+rz0*rz0;
    const float dd1 = rx1*rx1+ry1*ry1+rz1*rz1;
    const float dd2 = rx2*rx2+ry2*ry2+rz2*rz2;
    const float dd3 = rx3*rx3+ry3*ry3+rz3*rz3;

    // run structure (once)
    const float e01 = (d_0 == d_1) ? 1.f : 0.f;
    const float e12 = (d_1 == d_2) ? 1.f : 0.f;
    const float e23 = (d_2 == d_3) ? 1.f : 0.f;
    const float full0 = e01 * e12 * e23;
    const float f1 = e12 * e23;
    const float f2 = e23;
    // key-chain multipliers (once)
    float fullf = full0;
    int tk = d_3;
    const int hk = d_0;
    float ad_1, ad_2, ad_3, ad_4;
    KEYSTEP(4, ad_1) KEYSTEP(8, ad_2) KEYSTEP(16, ad_3) KEYSTEP(32, ad_4)
    const int g1hk = __shfl_down(d_0, 4);
    const float sf = (((wl + 4) < 64) && (d_3 == g1hk)) ? 1.f : 0.f;
    const int pd = __shfl_up(d_3, 4);
    const bool h0 = (quad == 0) || (pd != d_0);
    const bool h1 = (e01 == 0.f);
    const bool h2 = (e12 == 0.f);
    const bool h3 = (e23 == 0.f);

    // prefetch channel-0 gathers
    f32x16 A0, A1, A2, A3;
    GATHER(0)

    #pragma unroll 1
    for (int ch = 0; ch < CC; ++ch) {
        __syncthreads();   // previous channel's LDS reads complete
        // ---- stage W2, PW1 + vectors for this channel ----
        {
            const float4* g2 = (const float4*)(ew2 + (size_t)ch * DH * DH);
            float4* l2 = (float4*)sW2;
            #pragma unroll
            for (int i = 0; i < 4; ++i) l2[tid + i * 256] = g2[tid + i * 256];
            const float4* g3 = (const float4*)(pw1 + (size_t)ch * DH * DH);
            float4* l3 = (float4*)sPW1;
            #pragma unroll
            for (int i = 0; i < 4; ++i) l3[tid + i * 256] = g3[tid + i * 256];
            if (tid < DH) {
                sB2[tid]  = eb2[(size_t)ch * DH + tid];
                sPB1[tid] = pb1[(size_t)ch * DH + tid];
                sGW[tid]  = gw[(size_t)ch * DH + tid];
                sPW2[tid] = pw2[(size_t)ch * DH + tid];
            }
        }
        f32x16 W128v;
        LOAD16(W128v, ew1 + (size_t)ch * (2 * DH + 1) * DH + (size_t)(2 * DH) * DH + ck * 16)
        const float GB = gb[ch];
        __syncthreads();

        // ---- m1 = silu(A + d2*w128) ----
        FMAV(A0, W128v, dd0) FMAV(A1, W128v, dd1) FMAV(A2, W128v, dd2) FMAV(A3, W128v, dd3)
        SILU16(A0) SILU16(A1) SILU16(A2) SILU16(A3)

        // ---- m2 = silu(m1 @ W2 + B2) ----
        f32x16 B0v, B1v, B2v, B3v;
        { f32x16 bz; LOAD16(bz, sB2 + ck*16) B0v = bz; B1v = bz; B2v = bz; B3v = bz; }
        WBPHASE(sW2, 0, QB0, A0,A1,A2,A3, B0v,B1v,B2v,B3v)
        WBPHASE(sW2, 1, QB1, A0,A1,A2,A3, B0v,B1v,B2v,B3v)
        WBPHASE(sW2, 2, QB2, A0,A1,A2,A3, B0v,B1v,B2v,B3v)
        WBPHASE(sW2, 3, QB3, A0,A1,A2,A3, B0v,B1v,B2v,B3v)
        SILU16(B0v) SILU16(B1v) SILU16(B2v) SILU16(B3v)

        // ---- gate ----
        {
            f32x16 GWv; LOAD16(GWv, sGW + ck*16)
            float g0 = 0.f, g1 = 0.f, g2 = 0.f, g3 = 0.f;
            DOTV(g0, B0v, GWv) DOTV(g1, B1v, GWv) DOTV(g2, B2v, GWv) DOTV(g3, B3v, GWv)
            g0 += QPERM(g0, QXOR1); g0 += QPERM(g0, QXOR2);
            g1 += QPERM(g1, QXOR1); g1 += QPERM(g1, QXOR2);
            g2 += QPERM(g2, QXOR1); g2 += QPERM(g2, QXOR2);
            g3 += QPERM(g3, QXOR1); g3 += QPERM(g3, QXOR2);
            const float ga0 = sigmoidf_(GB + g0), ga1 = sigmoidf_(GB + g1);
            const float ga2 = sigmoidf_(GB + g2), ga3 = sigmoidf_(GB + g3);
            MUL16(B0v, ga0) MUL16(B1v, ga1) MUL16(B2v, ga2) MUL16(B3v, ga3)
        }

        // ---- q = silu(m @ PW1 + PB1); p = q @ PW2 ----  (q reuses A)
        { f32x16 bz; LOAD16(bz, sPB1 + ck*16) A0 = bz; A1 = bz; A2 = bz; A3 = bz; }
        WBPHASE(sPW1, 0, QB0, B0v,B1v,B2v,B3v, A0,A1,A2,A3)
        WBPHASE(sPW1, 1, QB1, B0v,B1v,B2v,B3v, A0,A1,A2,A3)
        WBPHASE(sPW1, 2, QB2, B0v,B1v,B2v,B3v, A0,A1,A2,A3)
        WBPHASE(sPW1, 3, QB3, B0v,B1v,B2v,B3v, A0,A1,A2,A3)
        SILU16(A0) SILU16(A1) SILU16(A2) SILU16(A3)
        float p0 = 0.f, p1 = 0.f, p2 = 0.f, p3 = 0.f;
        {
            f32x16 PW2v; LOAD16(PW2v, sPW2 + ck*16)
            DOTV(p0, A0, PW2v) DOTV(p1, A1, PW2v) DOTV(p2, A2, PW2v) DOTV(p3, A3, PW2v)
            p0 += QPERM(p0, QXOR1); p0 += QPERM(p0, QXOR2);
            p1 += QPERM(p1, QXOR1); p1 += QPERM(p1, QXOR2);
            p2 += QPERM(p2, QXOR1); p2 += QPERM(p2, QXOR2);
            p3 += QPERM(p3, QXOR1); p3 += QPERM(p3, QXOR2);
        }

        // A free: prefetch next channel's gathers (adjacent cache lines, cheap)
        if (ch < CC - 1) { GATHER(ch + 1) }

        float tx0 = fminf(fmaxf(rx0*p0, -2.f), 2.f), ty0 = fminf(fmaxf(ry0*p0, -2.f), 2.f), tz0 = fminf(fmaxf(rz0*p0, -2.f), 2.f);
        float tx1 = fminf(fmaxf(rx1*p1, -2.f), 2.f), ty1 = fminf(fmaxf(ry1*p1, -2.f), 2.f), tz1 = fminf(fmaxf(rz1*p1, -2.f), 2.f);
        float tx2 = fminf(fmaxf(rx2*p2, -2.f), 2.f), ty2 = fminf(fmaxf(ry2*p2, -2.f), 2.f), tz2 = fminf(fmaxf(rz2*p2, -2.f), 2.f);
        float tx3 = fminf(fmaxf(rx3*p3, -2.f), 2.f), ty3 = fminf(fmaxf(ry3*p3, -2.f), 2.f), tz3 = fminf(fmaxf(rz3*p3, -2.f), 2.f);

        // ---- in-lane suffix merge ----
        FMAV(B2v, B3v, e23) tx2 = fmaf(e23, tx3, tx2); ty2 = fmaf(e23, ty3, ty2); tz2 = fmaf(e23, tz3, tz2);
        FMAV(B1v, B2v, e12) tx1 = fmaf(e12, tx2, tx1); ty1 = fmaf(e12, ty2, ty1); tz1 = fmaf(e12, tz2, tz1);
        FMAV(B0v, B1v, e01) tx0 = fmaf(e01, tx1, tx0); ty0 = fmaf(e01, ty1, ty0); tz0 = fmaf(e01, tz1, tz0);

        // ---- cross-quad payload scan (keys precomputed) ----
        f32x16 Pv = B0v;
        float ppx = tx0, ppy = ty0, ppz = tz0;
        PAYSTEP(4, ad_1) PAYSTEP(8, ad_2) PAYSTEP(16, ad_3) PAYSTEP(32, ad_4)
        f32x16 Sv; SHFL16D(Sv, Pv, 4)
        float spx = __shfl_down(ppx, 4), spy = __shfl_down(ppy, 4), spz = __shfl_down(ppz, 4);
        MUL16(Sv, sf) spx *= sf; spy *= sf; spz *= sf;

#define FLUSH(COND, DJ, BV, F, TX, TY, TZ) \
        if (COND) { \
            float* ar = agg + ((size_t)ch * N + (DJ)) * DH + ck * 16; \
            atomicAdd(ar+0,  BV[0]+(F)*Sv[0]);   atomicAdd(ar+1,  BV[1]+(F)*Sv[1]); \
            atomicAdd(ar+2,  BV[2]+(F)*Sv[2]);   atomicAdd(ar+3,  BV[3]+(F)*Sv[3]); \
            atomicAdd(ar+4,  BV[4]+(F)*Sv[4]);   atomicAdd(ar+5,  BV[5]+(F)*Sv[5]); \
            atomicAdd(ar+6,  BV[6]+(F)*Sv[6]);   atomicAdd(ar+7,  BV[7]+(F)*Sv[7]); \
            atomicAdd(ar+8,  BV[8]+(F)*Sv[8]);   atomicAdd(ar+9,  BV[9]+(F)*Sv[9]); \
            atomicAdd(ar+10, BV[10]+(F)*Sv[10]); atomicAdd(ar+11, BV[11]+(F)*Sv[11]); \
            atomicAdd(ar+12, BV[12]+(F)*Sv[12]); atomicAdd(ar+13, BV[13]+(F)*Sv[13]); \
            atomicAdd(ar+14, BV[14]+(F)*Sv[14]); atomicAdd(ar+15, BV[15]+(F)*Sv[15]); \
            if (ck == 0) { \
                atomicAdd(&pos_acc[(DJ)*3+0], (TX)+(F)*spx); \
                atomicAdd(&pos_acc[(DJ)*3+1], (TY)+(F)*spy); \
                atomicAdd(&pos_acc[(DJ)*3+2], (TZ)+(F)*spz); } }

        FLUSH(h0, d_0, B0v, full0, tx0, ty0, tz0)
        FLUSH(h1, d_1, B1v, f1,    tx1, ty1, tz1)
        FLUSH(h2, d_2, B2v, f2,    tx2, ty2, tz2)
        FLUSH(h3, d_3, B3v, 1.0f,  tx3, ty3, tz3)
#undef FLUSH
    }
}

// ---------------- node update ----------------
__global__ __launch_bounds__(256) void node_kernel(
        const float* __restrict__ h, float* __restrict__ agg,
        const float* __restrict__ nw, const float* __restrict__ nb, int N) {
    const int c = blockIdx.y;
    const int wave = threadIdx.x >> 6, lane = threadIdx.x & 63;
    const int i = blockIdx.x * 4 + wave;
    if (i >= N) return;
    const float* hrow = h + ((size_t)c * N + i) * DH;
    float* arow = agg + ((size_t)c * N + i) * DH;
    const float* W = nw + (size_t)c * (2 * DH) * DH;
    float acc = nb[(size_t)c * DH + lane];
    #pragma unroll 8
    for (int k = 0; k < DH; ++k) acc += hrow[k] * W[(size_t)k * DH + lane];
    #pragma unroll 8
    for (int k = 0; k < DH; ++k) acc += arow[k] * W[(size_t)(DH + k) * DH + lane];
    arow[lane] = acc;
}

// ---------------- mix_out ----------------
__global__ __launch_bounds__(256) void mix_out_kernel(
        const float* __restrict__ hout, const float* __restrict__ W,
        float* __restrict__ x, int N) {
    __shared__ float hs[8][CC * DH];
    const int i0 = blockIdx.x * 8;
    const int tid = threadIdx.x;
    for (int t = tid; t < 8 * CC * DH; t += 256) {
        int j = t >> 8, cd = t & 255;
        int c = cd >> 6, d = cd & 63;
        int i = i0 + j;
        hs[j][cd] = (i < N) ? hout[((size_t)c * N + i) * DH + d] : 0.f;
    }
    __syncthreads();
    const int o = tid & 127, g = tid >> 7;
    float acc[4] = {0.f, 0.f, 0.f, 0.f};
    for (int cd = 0; cd < CC * DH; ++cd) {
        float w = W[(size_t)cd * DIN + o];
        #pragma unroll
        for (int j = 0; j < 4; ++j) acc[j] += hs[g * 4 + j][cd] * w;
    }
    #pragma unroll
    for (int j = 0; j < 4; ++j) {
        int i = i0 + g * 4 + j;
        if (i < N) x[(size_t)i * DIN + o] += acc[j];
    }
}

// ---------------- pos finalize ----------------
__global__ void pos_fin_kernel(float* __restrict__ pos, const float* __restrict__ pos_acc,
                               const int* __restrict__ cnt, int N) {
    int i = blockIdx.x * 256 + threadIdx.x;
    if (i < N) {
        float inv = 1.0f / ((float)CC * fmaxf((float)cnt[i], 1.0f));
        pos[i * 3 + 0] += pos_acc[i * 3 + 0] * inv;
        pos[i * 3 + 1] += pos_acc[i * 3 + 1] * inv;
        pos[i * 3 + 2] += pos_acc[i * 3 + 2] * inv;
    }
}

extern "C" void kernel_launch(void* const* d_in, const int* in_sizes, int n_in,
                              void* d_out, int out_size, void* d_ws, size_t ws_size,
                              hipStream_t stream) {
    const float* x         = (const float*)d_in[0];
    const float* pos       = (const float*)d_in[1];
    const int*   ei        = (const int*)d_in[2];
    const float* mix_in_w  = (const float*)d_in[3];
    const float* mix_out_w = (const float*)d_in[4];
    const float* ew1       = (const float*)d_in[5];
    const float* eb1       = (const float*)d_in[6];
    const float* ew2       = (const float*)d_in[7];
    const float* eb2       = (const float*)d_in[8];
    const float* gw        = (const float*)d_in[9];
    const float* gb        = (const float*)d_in[10];
    const float* nw        = (const float*)d_in[11];
    const float* nb        = (const float*)d_in[12];
    const float* pw1       = (const float*)d_in[13];
    const float* pb1       = (const float*)d_in[14];
    const float* pw2       = (const float*)d_in[15];

    const int* src = ei;
    const int* dst = ei + EE;

    float* xout    = (float*)d_out;
    float* pos_out = xout + (size_t)NN * DIN;

    float* hbuf    = (float*)d_ws;                     // C*N*64
    float* aggb    = hbuf + (size_t)CC * NN * DH;      // C*N*64
    float* hsp     = aggb + (size_t)CC * NN * DH;      // N*C*64 (node-interleaved)
    float* hdp     = hsp  + (size_t)CC * NN * DH;      // N*C*64 (node-interleaved)
    float* pos_cur = hdp  + (size_t)CC * NN * DH;      // N*3
    float* pos_acc = pos_cur + (size_t)NN * 3;         // N*3
    int*   cnt_i   = (int*)(pos_acc + (size_t)NN * 3); // N
    int*   offs    = cnt_i + NN;                       // N
    int*   fill    = offs + NN;                        // N
    int*   bsum    = fill + NN;                        // 256
    int*   ssrc    = bsum + 256;                       // E
    int*   sdst    = ssrc + EE;                        // E

    const int NB = (NN + 255) / 256;

    hipMemcpyAsync(xout, x, sizeof(float) * NN * DIN, hipMemcpyDeviceToDevice, stream);
    hipMemcpyAsync(pos_cur, pos, sizeof(float) * NN * 3, hipMemcpyDeviceToDevice, stream);
    hipMemsetAsync(cnt_i, 0, sizeof(int) * NN, stream);
    hipMemsetAsync(fill, 0, sizeof(int) * NN, stream);

    cnt_kernel<<<(EE + 255) / 256, 256, 0, stream>>>(dst, cnt_i, EE);
    scan1<<<NB, 256, 0, stream>>>(cnt_i, offs, bsum, NN);
    scan2<<<1, 256, 0, stream>>>(bsum, NB);
    scan3<<<NB, 256, 0, stream>>>(offs, bsum, NN);
    order_kernel<<<(EE + 255) / 256, 256, 0, stream>>>(src, dst, offs, fill, ssrc, sdst, EE);

    for (int l = 0; l < LL; ++l) {
        hipMemsetAsync(aggb, 0, sizeof(float) * CC * NN * DH, stream);
        hipMemsetAsync(pos_acc, 0, sizeof(float) * NN * 3, stream);

        mix_in_kernel<<<(NN + 7) / 8, 256, 0, stream>>>(
            xout, mix_in_w + (size_t)l * DIN * CC * DH, hbuf, NN);

        pre_kernel<<<dim3((NN + 3) / 4, CC), 256, 0, stream>>>(
            hbuf,
            ew1 + (size_t)l * CC * (2 * DH + 1) * DH,
            eb1 + (size_t)l * CC * DH,
            hsp, hdp, NN);

        edge_kernel<<<EE / 256, 256, 0, stream>>>(
            hsp, hdp, pos_cur, ssrc, sdst,
            ew1 + (size_t)l * CC * (2 * DH + 1) * DH,
            ew2 + (size_t)l * CC * DH * DH,
            eb2 + (size_t)l * CC * DH,
            gw  + (size_t)l * CC * DH,
            gb  + (size_t)l * CC,
            pw1 + (size_t)l * CC * DH * DH,
            pb1 + (size_t)l * CC * DH,
            pw2 + (size_t)l * CC * DH,
            aggb, pos_acc, EE, NN);

        node_kernel<<<dim3((NN + 3) / 4, CC), 256, 0, stream>>>(
            hbuf, aggb,
            nw + (size_t)l * CC * 2 * DH * DH,
            nb + (size_t)l * CC * DH, NN);

        mix_out_kernel<<<(NN + 7) / 8, 256, 0, stream>>>(
            aggb, mix_out_w + (size_t)l * CC * DH * DIN, xout, NN);

        pos_fin_kernel<<<(NN + 255) / 256, 256, 0, stream>>>(pos_cur, pos_acc, cnt_i, NN);
    }

    hipMemcpyAsync(pos_out, pos_cur, sizeof(float) * NN * 3, hipMemcpyDeviceToDevice, stream);
}

// Round 14
// 6547.325 us; speedup vs baseline: 1.1545x; 1.1492x over previous
//
#include <hip/hip_runtime.h>

#define NN 50000
#define EE 800000
#define DIN 128
#define DH 64
#define CC 4
#define LL 3

typedef float f32x16 __attribute__((ext_vector_type(16)));

__device__ __forceinline__ float sigmoidf_(float x) {
    return __builtin_amdgcn_rcpf(1.0f + __expf(-x));
}

// DPP quad_perm broadcast/permute (VALU-only cross-lane within groups of 4)
#define QPERM(x, CTRL) (__int_as_float(__builtin_amdgcn_update_dpp(0, __float_as_int(x), (CTRL), 0xF, 0xF, true)))
#define QB0 0x00
#define QB1 0x55
#define QB2 0xAA
#define QB3 0xFF
#define QXOR1 0xB1   // [1,0,3,2]
#define QXOR2 0x4E   // [2,3,0,1]

// memory assembly kept as float4 loads (alignment-safe); ALU ops below are
// whole-vector expressions so the backend can legalize to v_pk_fma_f32.
#define LOAD16(V, P) { const float4* _p4 = (const float4*)(P); \
    float4 _a=_p4[0], _b=_p4[1], _c=_p4[2], _d=_p4[3]; \
    V[0]=_a.x; V[1]=_a.y; V[2]=_a.z; V[3]=_a.w; \
    V[4]=_b.x; V[5]=_b.y; V[6]=_b.z; V[7]=_b.w; \
    V[8]=_c.x; V[9]=_c.y; V[10]=_c.z; V[11]=_c.w; \
    V[12]=_d.x; V[13]=_d.y; V[14]=_d.z; V[15]=_d.w; }

#define ADD16(V, U) { V += (U); }
#define FMAV(V, W, xv) { V += (W) * (xv); }
#define MUL16(V, s) { V *= (s); }

#define SILU16(V) { \
    V[0]*=sigmoidf_(V[0]);  V[1]*=sigmoidf_(V[1]);  V[2]*=sigmoidf_(V[2]);  V[3]*=sigmoidf_(V[3]); \
    V[4]*=sigmoidf_(V[4]);  V[5]*=sigmoidf_(V[5]);  V[6]*=sigmoidf_(V[6]);  V[7]*=sigmoidf_(V[7]); \
    V[8]*=sigmoidf_(V[8]);  V[9]*=sigmoidf_(V[9]);  V[10]*=sigmoidf_(V[10]); V[11]*=sigmoidf_(V[11]); \
    V[12]*=sigmoidf_(V[12]); V[13]*=sigmoidf_(V[13]); V[14]*=sigmoidf_(V[14]); V[15]*=sigmoidf_(V[15]); }

#define DOTV(acc, V, W) { const f32x16 _m = (V) * (W); \
    acc += _m[0]+_m[1]+_m[2]+_m[3]+_m[4]+_m[5]+_m[6]+_m[7] \
         +_m[8]+_m[9]+_m[10]+_m[11]+_m[12]+_m[13]+_m[14]+_m[15]; }

#define SHFL16D(D, Ssrc, SS) { \
    D[0]=__shfl_down(Ssrc[0],SS);  D[1]=__shfl_down(Ssrc[1],SS); \
    D[2]=__shfl_down(Ssrc[2],SS);  D[3]=__shfl_down(Ssrc[3],SS); \
    D[4]=__shfl_down(Ssrc[4],SS);  D[5]=__shfl_down(Ssrc[5],SS); \
    D[6]=__shfl_down(Ssrc[6],SS);  D[7]=__shfl_down(Ssrc[7],SS); \
    D[8]=__shfl_down(Ssrc[8],SS);  D[9]=__shfl_down(Ssrc[9],SS); \
    D[10]=__shfl_down(Ssrc[10],SS); D[11]=__shfl_down(Ssrc[11],SS); \
    D[12]=__shfl_down(Ssrc[12],SS); D[13]=__shfl_down(Ssrc[13],SS); \
    D[14]=__shfl_down(Ssrc[14],SS); D[15]=__shfl_down(Ssrc[15],SS); }

// W2/PW1 k-step: DPP-broadcast source element r from quad lane of phase
#define WBK(WSRC, KK, QB, S0,S1,S2,S3, D0,D1,D2,D3, RR) { f32x16 Wv; \
    LOAD16(Wv, (WSRC) + (size_t)(KK)*DH + ck*16) \
    { const float _m0=QPERM(S0[RR],QB), _m1=QPERM(S1[RR],QB), _m2=QPERM(S2[RR],QB), _m3=QPERM(S3[RR],QB); \
      FMAV(D0,Wv,_m0) FMAV(D1,Wv,_m1) FMAV(D2,Wv,_m2) FMAV(D3,Wv,_m3) } }

#define WBPHASE(WSRC, P4, QB, S0,S1,S2,S3, D0,D1,D2,D3) \
    WBK(WSRC,(P4)*16+0, QB,S0,S1,S2,S3,D0,D1,D2,D3,0)  WBK(WSRC,(P4)*16+1, QB,S0,S1,S2,S3,D0,D1,D2,D3,1)  \
    WBK(WSRC,(P4)*16+2, QB,S0,S1,S2,S3,D0,D1,D2,D3,2)  WBK(WSRC,(P4)*16+3, QB,S0,S1,S2,S3,D0,D1,D2,D3,3)  \
    WBK(WSRC,(P4)*16+4, QB,S0,S1,S2,S3,D0,D1,D2,D3,4)  WBK(WSRC,(P4)*16+5, QB,S0,S1,S2,S3,D0,D1,D2,D3,5)  \
    WBK(WSRC,(P4)*16+6, QB,S0,S1,S2,S3,D0,D1,D2,D3,6)  WBK(WSRC,(P4)*16+7, QB,S0,S1,S2,S3,D0,D1,D2,D3,7)  \
    WBK(WSRC,(P4)*16+8, QB,S0,S1,S2,S3,D0,D1,D2,D3,8)  WBK(WSRC,(P4)*16+9, QB,S0,S1,S2,S3,D0,D1,D2,D3,9)  \
    WBK(WSRC,(P4)*16+10,QB,S0,S1,S2,S3,D0,D1,D2,D3,10) WBK(WSRC,(P4)*16+11,QB,S0,S1,S2,S3,D0,D1,D2,D3,11) \
    WBK(WSRC,(P4)*16+12,QB,S0,S1,S2,S3,D0,D1,D2,D3,12) WBK(WSRC,(P4)*16+13,QB,S0,S1,S2,S3,D0,D1,D2,D3,13) \
    WBK(WSRC,(P4)*16+14,QB,S0,S1,S2,S3,D0,D1,D2,D3,14) WBK(WSRC,(P4)*16+15,QB,S0,S1,S2,S3,D0,D1,D2,D3,15)

// chain-scan combine step across quads (stride SS lanes)
#define SCANSTEP(SS) { \
    f32x16 bP; SHFL16D(bP, Pv, SS) \
    float bpx=__shfl_down(ppx,SS), bpy=__shfl_down(ppy,SS), bpz=__shfl_down(ppz,SS); \
    int   bhk=__shfl_down(hk,SS), btk=__shfl_down(tk,SS); \
    float bfl=__shfl_down(fullf,SS); \
    const bool vq = (wl + SS) < 64; \
    const float mt = (vq && (tk==bhk)) ? 1.0f : 0.0f; \
    const float ad = fullf*mt; \
    FMAV(Pv, bP, ad) ppx=fmaf(ad,bpx,ppx); ppy=fmaf(ad,bpy,ppy); ppz=fmaf(ad,bpz,ppz); \
    const float nf = fullf*bfl*mt; \
    fullf = vq ? nf : fullf; \
    tk    = vq ? btk : tk; }

// ---------------- degree count ----------------
__global__ void cnt_kernel(const int* __restrict__ dst, int* __restrict__ cnt, int E) {
    int e = blockIdx.x * 256 + threadIdx.x;
    if (e < E) atomicAdd(&cnt[dst[e]], 1);
}

// ---------------- scans ----------------
__global__ __launch_bounds__(256) void scan1(const int* __restrict__ cnt, int* __restrict__ offs,
                                             int* __restrict__ bsum, int N) {
    __shared__ int sh[256];
    int i = blockIdx.x * 256 + threadIdx.x;
    int v = (i < N) ? cnt[i] : 0;
    sh[threadIdx.x] = v; __syncthreads();
    for (int s = 1; s < 256; s <<= 1) {
        int a = (threadIdx.x >= s) ? sh[threadIdx.x - s] : 0;
        __syncthreads(); sh[threadIdx.x] += a; __syncthreads();
    }
    int incl = sh[threadIdx.x];
    if (i < N) offs[i] = incl - v;
    if (threadIdx.x == 255) bsum[blockIdx.x] = incl;
}
__global__ __launch_bounds__(256) void scan2(int* __restrict__ bsum, int nb) {
    __shared__ int sh[256];
    int v = (threadIdx.x < nb) ? bsum[threadIdx.x] : 0;
    sh[threadIdx.x] = v; __syncthreads();
    for (int s = 1; s < 256; s <<= 1) {
        int a = (threadIdx.x >= s) ? sh[threadIdx.x - s] : 0;
        __syncthreads(); sh[threadIdx.x] += a; __syncthreads();
    }
    if (threadIdx.x < nb) bsum[threadIdx.x] = sh[threadIdx.x] - v;
}
__global__ void scan3(int* __restrict__ offs, const int* __restrict__ bsum, int N) {
    int i = blockIdx.x * 256 + threadIdx.x;
    if (i < N) offs[i] += bsum[blockIdx.x];
}

// ---------------- counting-sort by dst ----------------
__global__ void order_kernel(const int* __restrict__ src, const int* __restrict__ dst,
                             const int* __restrict__ offs, int* __restrict__ fill,
                             int* __restrict__ ssrc, int* __restrict__ sdst, int E) {
    int e = blockIdx.x * 256 + threadIdx.x;
    if (e < E) {
        int d = dst[e];
        int slot = offs[d] + atomicAdd(&fill[d], 1);
        ssrc[slot] = src[e];
        sdst[slot] = d;
    }
}

// ---------------- mix_in ----------------
__global__ __launch_bounds__(256) void mix_in_kernel(
        const float* __restrict__ x, const float* __restrict__ W,
        float* __restrict__ h, int N) {
    __shared__ float xs[8][DIN];
    const int i0 = blockIdx.x * 8;
    const int tid = threadIdx.x;
    for (int t = tid; t < 8 * DIN; t += 256) {
        int j = t / DIN, k = t % DIN;
        int i = i0 + j;
        xs[j][k] = (i < N) ? x[(size_t)i * DIN + k] : 0.f;
    }
    __syncthreads();
    float acc[8] = {0.f, 0.f, 0.f, 0.f, 0.f, 0.f, 0.f, 0.f};
    for (int k = 0; k < DIN; ++k) {
        float w = W[k * (CC * DH) + tid];
        #pragma unroll
        for (int j = 0; j < 8; ++j) acc[j] += xs[j][k] * w;
    }
    const int c = tid >> 6, d = tid & 63;
    #pragma unroll
    for (int j = 0; j < 8; ++j) {
        int i = i0 + j;
        if (i < N) h[((size_t)c * N + i) * DH + d] = acc[j];
    }
}

// ---------------- pre_kernel: hsp = h@W1s ; hdp = h@W1d + B1 (per node, per channel) ----------------
__global__ __launch_bounds__(256) void pre_kernel(
        const float* __restrict__ h, const float* __restrict__ ew1,
        const float* __restrict__ eb1,
        float* __restrict__ hsp, float* __restrict__ hdp, int N) {
    const int c = blockIdx.y;
    const int wave = threadIdx.x >> 6, lane = threadIdx.x & 63;
    const int i = blockIdx.x * 4 + wave;
    if (i >= N) return;
    const float* hrow = h + ((size_t)c * N + i) * DH;
    const float* W1 = ew1 + (size_t)c * (2 * DH + 1) * DH;
    float a_s = 0.f;
    float a_d = eb1[(size_t)c * DH + lane];
    #pragma unroll 8
    for (int k = 0; k < DH; ++k) {
        const float hv = hrow[k];
        a_s += hv * W1[(size_t)k * DH + lane];
        a_d += hv * W1[(size_t)(DH + k) * DH + lane];
    }
    hsp[((size_t)c * N + i) * DH + lane] = a_s;
    hdp[((size_t)c * N + i) * DH + lane] = a_d;
}

// ---------------- edge kernel: quad decomposition, precomputed W1 halves ----------------
// m1 = silu(hsp[src] + hdp[dst] + d2*w1_row128); then W2/PW1 (LDS, DPP).
__global__ __launch_bounds__(256, 2) void edge_kernel(
    const float* __restrict__ hsp, const float* __restrict__ hdp,
    const float* __restrict__ pos,
    const int* __restrict__ ssrc, const int* __restrict__ sdst,
    const float* __restrict__ ew1,
    const float* __restrict__ ew2, const float* __restrict__ eb2,
    const float* __restrict__ gw,  const float* __restrict__ gb,
    const float* __restrict__ pw1, const float* __restrict__ pb1,
    const float* __restrict__ pw2,
    float* __restrict__ agg, float* __restrict__ pos_acc,
    int E, int N)
{
    __shared__ float sW2[DH * DH];             // 16 KB
    __shared__ float sPW1[DH * DH];            // 16 KB
    __shared__ float sB2[DH], sPB1[DH], sGW[DH], sPW2[DH];

    const int ch = blockIdx.y;
    const int tid = threadIdx.x;

    // stage W2, PW1 + small vectors to LDS
    {
        const float4* g2 = (const float4*)(ew2 + (size_t)ch * DH * DH);
        float4* l2 = (float4*)sW2;
        #pragma unroll
        for (int i = 0; i < 4; ++i) l2[tid + i * 256] = g2[tid + i * 256];
        const float4* g3 = (const float4*)(pw1 + (size_t)ch * DH * DH);
        float4* l3 = (float4*)sPW1;
        #pragma unroll
        for (int i = 0; i < 4; ++i) l3[tid + i * 256] = g3[tid + i * 256];
        if (tid < DH) {
            sB2[tid]  = eb2[(size_t)ch * DH + tid];
            sPB1[tid] = pb1[(size_t)ch * DH + tid];
            sGW[tid]  = gw[(size_t)ch * DH + tid];
            sPW2[tid] = pw2[(size_t)ch * DH + tid];
        }
    }
    __syncthreads();

    const int wl   = tid & 63;
    const int ck   = wl & 3;
    const int quad = wl >> 2;
    const int qedge = blockIdx.x * 256 + (tid >> 6) * 64 + quad * 4;

    // per-lane W1 d2-row chunk (one-time global load, uniform per ck)
    f32x16 W128v;
    LOAD16(W128v, ew1 + (size_t)ch * (2 * DH + 1) * DH + (size_t)(2 * DH) * DH + ck * 16)

    const int4 s4 = *(const int4*)(ssrc + qedge);
    const int4 t4 = *(const int4*)(sdst + qedge);
    const int d_0 = t4.x, d_1 = t4.y, d_2 = t4.z, d_3 = t4.w;

    float rx0 = pos[3*s4.x+0]-pos[3*t4.x+0], ry0 = pos[3*s4.x+1]-pos[3*t4.x+1], rz0 = pos[3*s4.x+2]-pos[3*t4.x+2];
    float rx1 = pos[3*s4.y+0]-pos[3*t4.y+0], ry1 = pos[3*s4.y+1]-pos[3*t4.y+1], rz1 = pos[3*s4.y+2]-pos[3*t4.y+2];
    float rx2 = pos[3*s4.z+0]-pos[3*t4.z+0], ry2 = pos[3*s4.z+1]-pos[3*t4.z+1], rz2 = pos[3*s4.z+2]-pos[3*t4.z+2];
    float rx3 = pos[3*s4.w+0]-pos[3*t4.w+0], ry3 = pos[3*s4.w+1]-pos[3*t4.w+1], rz3 = pos[3*s4.w+2]-pos[3*t4.w+2];
    const float dd0 = rx0*rx0+ry0*ry0+rz0*rz0;
    const float dd1 = rx1*rx1+ry1*ry1+rz1*rz1;
    const float dd2 = rx2*rx2+ry2*ry2+rz2*rz2;
    const float dd3 = rx3*rx3+ry3*ry3+rz3*rz3;

    const float GB = gb[ch];
    const float* hsp_c = hsp + (size_t)ch * N * DH;
    const float* hdp_c = hdp + (size_t)ch * N * DH;

    // ---- m1 = silu(hsp[s] + hdp[t] + d2*w128) ----
    f32x16 A0, A1, A2, A3, T;
    LOAD16(A0, hsp_c + (size_t)s4.x * DH + ck*16)
    LOAD16(T,  hdp_c + (size_t)t4.x * DH + ck*16)  ADD16(A0, T)  FMAV(A0, W128v, dd0)
    LOAD16(A1, hsp_c + (size_t)s4.y * DH + ck*16)
    LOAD16(T,  hdp_c + (size_t)t4.y * DH + ck*16)  ADD16(A1, T)  FMAV(A1, W128v, dd1)
    LOAD16(A2, hsp_c + (size_t)s4.z * DH + ck*16)
    LOAD16(T,  hdp_c + (size_t)t4.z * DH + ck*16)  ADD16(A2, T)  FMAV(A2, W128v, dd2)
    LOAD16(A3, hsp_c + (size_t)s4.w * DH + ck*16)
    LOAD16(T,  hdp_c + (size_t)t4.w * DH + ck*16)  ADD16(A3, T)  FMAV(A3, W128v, dd3)
    SILU16(A0) SILU16(A1) SILU16(A2) SILU16(A3)

    // ---- m2 = silu(m1 @ W2 + B2) ----  (W2 from LDS)
    f32x16 B0v, B1v, B2v, B3v;
    { f32x16 bz; LOAD16(bz, sB2 + ck*16) B0v = bz; B1v = bz; B2v = bz; B3v = bz; }
    WBPHASE(sW2, 0, QB0, A0,A1,A2,A3, B0v,B1v,B2v,B3v)
    WBPHASE(sW2, 1, QB1, A0,A1,A2,A3, B0v,B1v,B2v,B3v)
    WBPHASE(sW2, 2, QB2, A0,A1,A2,A3, B0v,B1v,B2v,B3v)
    WBPHASE(sW2, 3, QB3, A0,A1,A2,A3, B0v,B1v,B2v,B3v)
    SILU16(B0v) SILU16(B1v) SILU16(B2v) SILU16(B3v)

    // ---- gate (quad reduce via DPP) ----
    {
        f32x16 GWv; LOAD16(GWv, sGW + ck*16)
        float g0 = 0.f, g1 = 0.f, g2 = 0.f, g3 = 0.f;
        DOTV(g0, B0v, GWv) DOTV(g1, B1v, GWv) DOTV(g2, B2v, GWv) DOTV(g3, B3v, GWv)
        g0 += QPERM(g0, QXOR1); g0 += QPERM(g0, QXOR2);
        g1 += QPERM(g1, QXOR1); g1 += QPERM(g1, QXOR2);
        g2 += QPERM(g2, QXOR1); g2 += QPERM(g2, QXOR2);
        g3 += QPERM(g3, QXOR1); g3 += QPERM(g3, QXOR2);
        const float ga0 = sigmoidf_(GB + g0), ga1 = sigmoidf_(GB + g1);
        const float ga2 = sigmoidf_(GB + g2), ga3 = sigmoidf_(GB + g3);
        MUL16(B0v, ga0) MUL16(B1v, ga1) MUL16(B2v, ga2) MUL16(B3v, ga3)
    }

    // ---- q = silu(m2 @ PW1 + PB1); p = q @ PW2 ----  (PW1 from LDS)
    { f32x16 bz; LOAD16(bz, sPB1 + ck*16) A0 = bz; A1 = bz; A2 = bz; A3 = bz; }
    WBPHASE(sPW1, 0, QB0, B0v,B1v,B2v,B3v, A0,A1,A2,A3)
    WBPHASE(sPW1, 1, QB1, B0v,B1v,B2v,B3v, A0,A1,A2,A3)
    WBPHASE(sPW1, 2, QB2, B0v,B1v,B2v,B3v, A0,A1,A2,A3)
    WBPHASE(sPW1, 3, QB3, B0v,B1v,B2v,B3v, A0,A1,A2,A3)
    SILU16(A0) SILU16(A1) SILU16(A2) SILU16(A3)
    float p0 = 0.f, p1 = 0.f, p2 = 0.f, p3 = 0.f;
    {
        f32x16 PW2v; LOAD16(PW2v, sPW2 + ck*16)
        DOTV(p0, A0, PW2v) DOTV(p1, A1, PW2v) DOTV(p2, A2, PW2v) DOTV(p3, A3, PW2v)
        p0 += QPERM(p0, QXOR1); p0 += QPERM(p0, QXOR2);
        p1 += QPERM(p1, QXOR1); p1 += QPERM(p1, QXOR2);
        p2 += QPERM(p2, QXOR1); p2 += QPERM(p2, QXOR2);
        p3 += QPERM(p3, QXOR1); p3 += QPERM(p3, QXOR2);
    }
    float tx0 = fminf(fmaxf(rx0*p0, -2.f), 2.f), ty0 = fminf(fmaxf(ry0*p0, -2.f), 2.f), tz0 = fminf(fmaxf(rz0*p0, -2.f), 2.f);
    float tx1 = fminf(fmaxf(rx1*p1, -2.f), 2.f), ty1 = fminf(fmaxf(ry1*p1, -2.f), 2.f), tz1 = fminf(fmaxf(rz1*p1, -2.f), 2.f);
    float tx2 = fminf(fmaxf(rx2*p2, -2.f), 2.f), ty2 = fminf(fmaxf(ry2*p2, -2.f), 2.f), tz2 = fminf(fmaxf(rz2*p2, -2.f), 2.f);
    float tx3 = fminf(fmaxf(rx3*p3, -2.f), 2.f), ty3 = fminf(fmaxf(ry3*p3, -2.f), 2.f), tz3 = fminf(fmaxf(rz3*p3, -2.f), 2.f);

    // ---- in-lane suffix merge over my 4 sorted edges ----
    const float e01 = (d_0 == d_1) ? 1.f : 0.f;
    const float e12 = (d_1 == d_2) ? 1.f : 0.f;
    const float e23 = (d_2 == d_3) ? 1.f : 0.f;
    FMAV(B2v, B3v, e23) tx2 = fmaf(e23, tx3, tx2); ty2 = fmaf(e23, ty3, ty2); tz2 = fmaf(e23, tz3, tz2);
    FMAV(B1v, B2v, e12) tx1 = fmaf(e12, tx2, tx1); ty1 = fmaf(e12, ty2, ty1); tz1 = fmaf(e12, tz2, tz1);
    FMAV(B0v, B1v, e01) tx0 = fmaf(e01, tx1, tx0); ty0 = fmaf(e01, ty1, ty0); tz0 = fmaf(e01, tz1, tz0);
    const float full0 = e01 * e12 * e23;
    const float f1 = e12 * e23;
    const float f2 = e23;

    // ---- cross-quad chain scan ----
    f32x16 Pv = B0v;
    float ppx = tx0, ppy = ty0, ppz = tz0;
    float fullf = full0;
    int hk = d_0, tk = d_3;
    SCANSTEP(4) SCANSTEP(8) SCANSTEP(16) SCANSTEP(32)
    f32x16 Sv; SHFL16D(Sv, Pv, 4)
    float spx = __shfl_down(ppx, 4), spy = __shfl_down(ppy, 4), spz = __shfl_down(ppz, 4);
    const int g1hk = __shfl_down(d_0, 4);
    const float sf = (((wl + 4) < 64) && (d_3 == g1hk)) ? 1.f : 0.f;
    MUL16(Sv, sf) spx *= sf; spy *= sf; spz *= sf;

    const int pd = __shfl_up(d_3, 4);
    const bool h0 = (quad == 0) || (pd != d_0);
    const bool h1 = (e01 == 0.f);
    const bool h2 = (e12 == 0.f);
    const bool h3 = (e23 == 0.f);

#define FLUSH(COND, DJ, BV, F, TX, TY, TZ) \
    if (COND) { \
        float* ar = agg + ((size_t)ch * N + (DJ)) * DH + ck * 16; \
        atomicAdd(ar+0,  BV[0]+(F)*Sv[0]);   atomicAdd(ar+1,  BV[1]+(F)*Sv[1]); \
        atomicAdd(ar+2,  BV[2]+(F)*Sv[2]);   atomicAdd(ar+3,  BV[3]+(F)*Sv[3]); \
        atomicAdd(ar+4,  BV[4]+(F)*Sv[4]);   atomicAdd(ar+5,  BV[5]+(F)*Sv[5]); \
        atomicAdd(ar+6,  BV[6]+(F)*Sv[6]);   atomicAdd(ar+7,  BV[7]+(F)*Sv[7]); \
        atomicAdd(ar+8,  BV[8]+(F)*Sv[8]);   atomicAdd(ar+9,  BV[9]+(F)*Sv[9]); \
        atomicAdd(ar+10, BV[10]+(F)*Sv[10]); atomicAdd(ar+11, BV[11]+(F)*Sv[11]); \
        atomicAdd(ar+12, BV[12]+(F)*Sv[12]); atomicAdd(ar+13, BV[13]+(F)*Sv[13]); \
        atomicAdd(ar+14, BV[14]+(F)*Sv[14]); atomicAdd(ar+15, BV[15]+(F)*Sv[15]); \
        if (ck == 0) { \
            atomicAdd(&pos_acc[(DJ)*3+0], (TX)+(F)*spx); \
            atomicAdd(&pos_acc[(DJ)*3+1], (TY)+(F)*spy); \
            atomicAdd(&pos_acc[(DJ)*3+2], (TZ)+(F)*spz); } }

    FLUSH(h0, d_0, B0v, full0, tx0, ty0, tz0)
    FLUSH(h1, d_1, B1v, f1,    tx1, ty1, tz1)
    FLUSH(h2, d_2, B2v, f2,    tx2, ty2, tz2)
    FLUSH(h3, d_3, B3v, 1.0f,  tx3, ty3, tz3)
#undef FLUSH
}

// ---------------- node update ----------------
__global__ __launch_bounds__(256) void node_kernel(
        const float* __restrict__ h, float* __restrict__ agg,
        const float* __restrict__ nw, const float* __restrict__ nb, int N) {
    const int c = blockIdx.y;
    const int wave = threadIdx.x >> 6, lane = threadIdx.x & 63;
    const int i = blockIdx.x * 4 + wave;
    if (i >= N) return;
    const float* hrow = h + ((size_t)c * N + i) * DH;
    float* arow = agg + ((size_t)c * N + i) * DH;
    const float* W = nw + (size_t)c * (2 * DH) * DH;
    float acc = nb[(size_t)c * DH + lane];
    #pragma unroll 8
    for (int k = 0; k < DH; ++k) acc += hrow[k] * W[(size_t)k * DH + lane];
    #pragma unroll 8
    for (int k = 0; k < DH; ++k) acc += arow[k] * W[(size_t)(DH + k) * DH + lane];
    arow[lane] = acc;
}

// ---------------- mix_out ----------------
__global__ __launch_bounds__(256) void mix_out_kernel(
        const float* __restrict__ hout, const float* __restrict__ W,
        float* __restrict__ x, int N) {
    __shared__ float hs[8][CC * DH];
    const int i0 = blockIdx.x * 8;
    const int tid = threadIdx.x;
    for (int t = tid; t < 8 * CC * DH; t += 256) {
        int j = t >> 8, cd = t & 255;
        int c = cd >> 6, d = cd & 63;
        int i = i0 + j;
        hs[j][cd] = (i < N) ? hout[((size_t)c * N + i) * DH + d] : 0.f;
    }
    __syncthreads();
    const int o = tid & 127, g = tid >> 7;
    float acc[4] = {0.f, 0.f, 0.f, 0.f};
    for (int cd = 0; cd < CC * DH; ++cd) {
        float w = W[(size_t)cd * DIN + o];
        #pragma unroll
        for (int j = 0; j < 4; ++j) acc[j] += hs[g * 4 + j][cd] * w;
    }
    #pragma unroll
    for (int j = 0; j < 4; ++j) {
        int i = i0 + g * 4 + j;
        if (i < N) x[(size_t)i * DIN + o] += acc[j];
    }
}

// ---------------- pos finalize ----------------
__global__ void pos_fin_kernel(float* __restrict__ pos, const float* __restrict__ pos_acc,
                               const int* __restrict__ cnt, int N) {
    int i = blockIdx.x * 256 + threadIdx.x;
    if (i < N) {
        float inv = 1.0f / ((float)CC * fmaxf((float)cnt[i], 1.0f));
        pos[i * 3 + 0] += pos_acc[i * 3 + 0] * inv;
        pos[i * 3 + 1] += pos_acc[i * 3 + 1] * inv;
        pos[i * 3 + 2] += pos_acc[i * 3 + 2] * inv;
    }
}

extern "C" void kernel_launch(void* const* d_in, const int* in_sizes, int n_in,
                              void* d_out, int out_size, void* d_ws, size_t ws_size,
                              hipStream_t stream) {
    const float* x         = (const float*)d_in[0];
    const float* pos       = (const float*)d_in[1];
    const int*   ei        = (const int*)d_in[2];
    const float* mix_in_w  = (const float*)d_in[3];
    const float* mix_out_w = (const float*)d_in[4];
    const float* ew1       = (const float*)d_in[5];
    const float* eb1       = (const float*)d_in[6];
    const float* ew2       = (const float*)d_in[7];
    const float* eb2       = (const float*)d_in[8];
    const float* gw        = (const float*)d_in[9];
    const float* gb        = (const float*)d_in[10];
    const float* nw        = (const float*)d_in[11];
    const float* nb        = (const float*)d_in[12];
    const float* pw1       = (const float*)d_in[13];
    const float* pb1       = (const float*)d_in[14];
    const float* pw2       = (const float*)d_in[15];

    const int* src = ei;
    const int* dst = ei + EE;

    float* xout    = (float*)d_out;
    float* pos_out = xout + (size_t)NN * DIN;

    float* hbuf    = (float*)d_ws;                     // C*N*64
    float* aggb    = hbuf + (size_t)CC * NN * DH;      // C*N*64
    float* hsp     = aggb + (size_t)CC * NN * DH;      // C*N*64
    float* hdp     = hsp  + (size_t)CC * NN * DH;      // C*N*64
    float* pos_cur = hdp  + (size_t)CC * NN * DH;      // N*3
    float* pos_acc = pos_cur + (size_t)NN * 3;         // N*3
    int*   cnt_i   = (int*)(pos_acc + (size_t)NN * 3); // N
    int*   offs    = cnt_i + NN;                       // N
    int*   fill    = offs + NN;                        // N
    int*   bsum    = fill + NN;                        // 256
    int*   ssrc    = bsum + 256;                       // E
    int*   sdst    = ssrc + EE;                        // E

    const int NB = (NN + 255) / 256;

    hipMemcpyAsync(xout, x, sizeof(float) * NN * DIN, hipMemcpyDeviceToDevice, stream);
    hipMemcpyAsync(pos_cur, pos, sizeof(float) * NN * 3, hipMemcpyDeviceToDevice, stream);
    hipMemsetAsync(cnt_i, 0, sizeof(int) * NN, stream);
    hipMemsetAsync(fill, 0, sizeof(int) * NN, stream);

    cnt_kernel<<<(EE + 255) / 256, 256, 0, stream>>>(dst, cnt_i, EE);
    scan1<<<NB, 256, 0, stream>>>(cnt_i, offs, bsum, NN);
    scan2<<<1, 256, 0, stream>>>(bsum, NB);
    scan3<<<NB, 256, 0, stream>>>(offs, bsum, NN);
    order_kernel<<<(EE + 255) / 256, 256, 0, stream>>>(src, dst, offs, fill, ssrc, sdst, EE);

    for (int l = 0; l < LL; ++l) {
        hipMemsetAsync(aggb, 0, sizeof(float) * CC * NN * DH, stream);
        hipMemsetAsync(pos_acc, 0, sizeof(float) * NN * 3, stream);

        mix_in_kernel<<<(NN + 7) / 8, 256, 0, stream>>>(
            xout, mix_in_w + (size_t)l * DIN * CC * DH, hbuf, NN);

        pre_kernel<<<dim3((NN + 3) / 4, CC), 256, 0, stream>>>(
            hbuf,
            ew1 + (size_t)l * CC * (2 * DH + 1) * DH,
            eb1 + (size_t)l * CC * DH,
            hsp, hdp, NN);

        edge_kernel<<<dim3(EE / 256, CC), 256, 0, stream>>>(
            hsp, hdp, pos_cur, ssrc, sdst,
            ew1 + (size_t)l * CC * (2 * DH + 1) * DH,
            ew2 + (size_t)l * CC * DH * DH,
            eb2 + (size_t)l * CC * DH,
            gw  + (size_t)l * CC * DH,
            gb  + (size_t)l * CC,
            pw1 + (size_t)l * CC * DH * DH,
            pb1 + (size_t)l * CC * DH,
            pw2 + (size_t)l * CC * DH,
            aggb, pos_acc, EE, NN);

        node_kernel<<<dim3((NN + 3) / 4, CC), 256, 0, stream>>>(
            hbuf, aggb,
            nw + (size_t)l * CC * 2 * DH * DH,
            nb + (size_t)l * CC * DH, NN);

        mix_out_kernel<<<(NN + 7) / 8, 256, 0, stream>>>(
            aggb, mix_out_w + (size_t)l * CC * DH * DIN, xout, NN);

        pos_fin_kernel<<<(NN + 255) / 256, 256, 0, stream>>>(pos_cur, pos_acc, cnt_i, NN);
    }

    hipMemcpyAsync(pos_out, pos_cur, sizeof(float) * NN * 3, hipMemcpyDeviceToDevice, stream);
}

// Round 15
// 5198.254 us; speedup vs baseline: 1.4541x; 1.2595x over previous
//
#include <hip/hip_runtime.h>

#define NN 50000
#define EE 800000
#define DIN 128
#define DH 64
#define CC 4
#define LL 3

typedef float f32x16 __attribute__((ext_vector_type(16)));

__device__ __forceinline__ float sigmoidf_(float x) {
    return __builtin_amdgcn_rcpf(1.0f + __expf(-x));
}

// DPP quad_perm broadcast/permute (VALU-only cross-lane within groups of 4)
#define QPERM(x, CTRL) (__int_as_float(__builtin_amdgcn_update_dpp(0, __float_as_int(x), (CTRL), 0xF, 0xF, true)))
#define QB0 0x00
#define QB1 0x55
#define QB2 0xAA
#define QB3 0xFF
#define QXOR1 0xB1   // [1,0,3,2]
#define QXOR2 0x4E   // [2,3,0,1]

// memory assembly kept as float4 loads (alignment-safe); ALU ops below are
// whole-vector expressions so the backend can legalize to v_pk_fma_f32.
#define LOAD16(V, P) { const float4* _p4 = (const float4*)(P); \
    float4 _a=_p4[0], _b=_p4[1], _c=_p4[2], _d=_p4[3]; \
    V[0]=_a.x; V[1]=_a.y; V[2]=_a.z; V[3]=_a.w; \
    V[4]=_b.x; V[5]=_b.y; V[6]=_b.z; V[7]=_b.w; \
    V[8]=_c.x; V[9]=_c.y; V[10]=_c.z; V[11]=_c.w; \
    V[12]=_d.x; V[13]=_d.y; V[14]=_d.z; V[15]=_d.w; }

#define ADD16(V, U) { V += (U); }
#define FMAV(V, W, xv) { V += (W) * (xv); }
#define MUL16(V, s) { V *= (s); }

#define SILU16(V) { \
    V[0]*=sigmoidf_(V[0]);  V[1]*=sigmoidf_(V[1]);  V[2]*=sigmoidf_(V[2]);  V[3]*=sigmoidf_(V[3]); \
    V[4]*=sigmoidf_(V[4]);  V[5]*=sigmoidf_(V[5]);  V[6]*=sigmoidf_(V[6]);  V[7]*=sigmoidf_(V[7]); \
    V[8]*=sigmoidf_(V[8]);  V[9]*=sigmoidf_(V[9]);  V[10]*=sigmoidf_(V[10]); V[11]*=sigmoidf_(V[11]); \
    V[12]*=sigmoidf_(V[12]); V[13]*=sigmoidf_(V[13]); V[14]*=sigmoidf_(V[14]); V[15]*=sigmoidf_(V[15]); }

#define DOTV(acc, V, W) { const f32x16 _m = (V) * (W); \
    acc += _m[0]+_m[1]+_m[2]+_m[3]+_m[4]+_m[5]+_m[6]+_m[7] \
         +_m[8]+_m[9]+_m[10]+_m[11]+_m[12]+_m[13]+_m[14]+_m[15]; }

#define SHFL16D(D, Ssrc, SS) { \
    D[0]=__shfl_down(Ssrc[0],SS);  D[1]=__shfl_down(Ssrc[1],SS); \
    D[2]=__shfl_down(Ssrc[2],SS);  D[3]=__shfl_down(Ssrc[3],SS); \
    D[4]=__shfl_down(Ssrc[4],SS);  D[5]=__shfl_down(Ssrc[5],SS); \
    D[6]=__shfl_down(Ssrc[6],SS);  D[7]=__shfl_down(Ssrc[7],SS); \
    D[8]=__shfl_down(Ssrc[8],SS);  D[9]=__shfl_down(Ssrc[9],SS); \
    D[10]=__shfl_down(Ssrc[10],SS); D[11]=__shfl_down(Ssrc[11],SS); \
    D[12]=__shfl_down(Ssrc[12],SS); D[13]=__shfl_down(Ssrc[13],SS); \
    D[14]=__shfl_down(Ssrc[14],SS); D[15]=__shfl_down(Ssrc[15],SS); }

// W2/PW1 k-step: DPP-broadcast source element r from quad lane of phase
#define WBK(WSRC, KK, QB, S0,S1,S2,S3, D0,D1,D2,D3, RR) { f32x16 Wv; \
    LOAD16(Wv, (WSRC) + (size_t)(KK)*DH + ck*16) \
    { const float _m0=QPERM(S0[RR],QB), _m1=QPERM(S1[RR],QB), _m2=QPERM(S2[RR],QB), _m3=QPERM(S3[RR],QB); \
      FMAV(D0,Wv,_m0) FMAV(D1,Wv,_m1) FMAV(D2,Wv,_m2) FMAV(D3,Wv,_m3) } }

#define WBPHASE(WSRC, P4, QB, S0,S1,S2,S3, D0,D1,D2,D3) \
    WBK(WSRC,(P4)*16+0, QB,S0,S1,S2,S3,D0,D1,D2,D3,0)  WBK(WSRC,(P4)*16+1, QB,S0,S1,S2,S3,D0,D1,D2,D3,1)  \
    WBK(WSRC,(P4)*16+2, QB,S0,S1,S2,S3,D0,D1,D2,D3,2)  WBK(WSRC,(P4)*16+3, QB,S0,S1,S2,S3,D0,D1,D2,D3,3)  \
    WBK(WSRC,(P4)*16+4, QB,S0,S1,S2,S3,D0,D1,D2,D3,4)  WBK(WSRC,(P4)*16+5, QB,S0,S1,S2,S3,D0,D1,D2,D3,5)  \
    WBK(WSRC,(P4)*16+6, QB,S0,S1,S2,S3,D0,D1,D2,D3,6)  WBK(WSRC,(P4)*16+7, QB,S0,S1,S2,S3,D0,D1,D2,D3,7)  \
    WBK(WSRC,(P4)*16+8, QB,S0,S1,S2,S3,D0,D1,D2,D3,8)  WBK(WSRC,(P4)*16+9, QB,S0,S1,S2,S3,D0,D1,D2,D3,9)  \
    WBK(WSRC,(P4)*16+10,QB,S0,S1,S2,S3,D0,D1,D2,D3,10) WBK(WSRC,(P4)*16+11,QB,S0,S1,S2,S3,D0,D1,D2,D3,11) \
    WBK(WSRC,(P4)*16+12,QB,S0,S1,S2,S3,D0,D1,D2,D3,12) WBK(WSRC,(P4)*16+13,QB,S0,S1,S2,S3,D0,D1,D2,D3,13) \
    WBK(WSRC,(P4)*16+14,QB,S0,S1,S2,S3,D0,D1,D2,D3,14) WBK(WSRC,(P4)*16+15,QB,S0,S1,S2,S3,D0,D1,D2,D3,15)

// chain-scan combine step across quads (stride SS lanes)
#define SCANSTEP(SS) { \
    f32x16 bP; SHFL16D(bP, Pv, SS) \
    float bpx=__shfl_down(ppx,SS), bpy=__shfl_down(ppy,SS), bpz=__shfl_down(ppz,SS); \
    int   bhk=__shfl_down(hk,SS), btk=__shfl_down(tk,SS); \
    float bfl=__shfl_down(fullf,SS); \
    const bool vq = (wl + SS) < 64; \
    const float mt = (vq && (tk==bhk)) ? 1.0f : 0.0f; \
    const float ad = fullf*mt; \
    FMAV(Pv, bP, ad) ppx=fmaf(ad,bpx,ppx); ppy=fmaf(ad,bpy,ppy); ppz=fmaf(ad,bpz,ppz); \
    const float nf = fullf*bfl*mt; \
    fullf = vq ? nf : fullf; \
    tk    = vq ? btk : tk; }

// ---------------- degree count ----------------
__global__ void cnt_kernel(const int* __restrict__ dst, int* __restrict__ cnt, int E) {
    int e = blockIdx.x * 256 + threadIdx.x;
    if (e < E) atomicAdd(&cnt[dst[e]], 1);
}

// ---------------- scans ----------------
__global__ __launch_bounds__(256) void scan1(const int* __restrict__ cnt, int* __restrict__ offs,
                                             int* __restrict__ bsum, int N) {
    __shared__ int sh[256];
    int i = blockIdx.x * 256 + threadIdx.x;
    int v = (i < N) ? cnt[i] : 0;
    sh[threadIdx.x] = v; __syncthreads();
    for (int s = 1; s < 256; s <<= 1) {
        int a = (threadIdx.x >= s) ? sh[threadIdx.x - s] : 0;
        __syncthreads(); sh[threadIdx.x] += a; __syncthreads();
    }
    int incl = sh[threadIdx.x];
    if (i < N) offs[i] = incl - v;
    if (threadIdx.x == 255) bsum[blockIdx.x] = incl;
}
__global__ __launch_bounds__(256) void scan2(int* __restrict__ bsum, int nb) {
    __shared__ int sh[256];
    int v = (threadIdx.x < nb) ? bsum[threadIdx.x] : 0;
    sh[threadIdx.x] = v; __syncthreads();
    for (int s = 1; s < 256; s <<= 1) {
        int a = (threadIdx.x >= s) ? sh[threadIdx.x - s] : 0;
        __syncthreads(); sh[threadIdx.x] += a; __syncthreads();
    }
    if (threadIdx.x < nb) bsum[threadIdx.x] = sh[threadIdx.x] - v;
}
__global__ void scan3(int* __restrict__ offs, const int* __restrict__ bsum, int N) {
    int i = blockIdx.x * 256 + threadIdx.x;
    if (i < N) offs[i] += bsum[blockIdx.x];
}

// ---------------- counting-sort by dst ----------------
__global__ void order_kernel(const int* __restrict__ src, const int* __restrict__ dst,
                             const int* __restrict__ offs, int* __restrict__ fill,
                             int* __restrict__ ssrc, int* __restrict__ sdst, int E) {
    int e = blockIdx.x * 256 + threadIdx.x;
    if (e < E) {
        int d = dst[e];
        int slot = offs[d] + atomicAdd(&fill[d], 1);
        ssrc[slot] = src[e];
        sdst[slot] = d;
    }
}

// ---------------- fused_in: mix_in + pre (h, hsp, hdp for 8 nodes) ----------------
// thread (c = tid>>6, d = tid&63); wave == one channel (weight rows coalesce).
__global__ __launch_bounds__(256) void fused_in_kernel(
        const float* __restrict__ x, const float* __restrict__ Wmix,
        const float* __restrict__ ew1, const float* __restrict__ eb1,
        float* __restrict__ h, float* __restrict__ hsp, float* __restrict__ hdp,
        int N) {
    __shared__ float xs[8][DIN];       // 4 KB
    __shared__ float hs[8][CC * DH];   // 8 KB
    const int i0 = blockIdx.x * 8;
    const int tid = threadIdx.x;
    const int c = tid >> 6, d = tid & 63;

    for (int t = tid; t < 8 * DIN; t += 256) {
        int j = t / DIN, k = t % DIN;
        int i = i0 + j;
        xs[j][k] = (i < N) ? x[(size_t)i * DIN + k] : 0.f;
    }
    __syncthreads();

    // mix_in: acc[j] = x[i0+j] @ Wmix[:, tid]
    float acc[8] = {0.f, 0.f, 0.f, 0.f, 0.f, 0.f, 0.f, 0.f};
    for (int k = 0; k < DIN; ++k) {
        float w = Wmix[k * (CC * DH) + tid];
        #pragma unroll
        for (int j = 0; j < 8; ++j) acc[j] += xs[j][k] * w;
    }
    #pragma unroll
    for (int j = 0; j < 8; ++j) {
        hs[j][tid] = acc[j];
        int i = i0 + j;
        if (i < N) h[((size_t)c * N + i) * DH + d] = acc[j];
    }
    __syncthreads();

    // pre: hsp = h@W1s ; hdp = h@W1d + B1  (h rows via LDS broadcast)
    const float* W1 = ew1 + (size_t)c * (2 * DH + 1) * DH;
    float a_s[8] = {0.f, 0.f, 0.f, 0.f, 0.f, 0.f, 0.f, 0.f};
    float a_d[8] = {0.f, 0.f, 0.f, 0.f, 0.f, 0.f, 0.f, 0.f};
    #pragma unroll 4
    for (int k = 0; k < DH; ++k) {
        const float w_s = W1[(size_t)k * DH + d];
        const float w_d = W1[(size_t)(DH + k) * DH + d];
        #pragma unroll
        for (int j = 0; j < 8; ++j) {
            const float hv = hs[j][c * DH + k];
            a_s[j] += hv * w_s;
            a_d[j] += hv * w_d;
        }
    }
    const float b1 = eb1[(size_t)c * DH + d];
    #pragma unroll
    for (int j = 0; j < 8; ++j) {
        int i = i0 + j;
        if (i < N) {
            hsp[((size_t)c * N + i) * DH + d] = a_s[j];
            hdp[((size_t)c * N + i) * DH + d] = a_d[j] + b1;
        }
    }
}

// ---------------- edge kernel: quad decomposition, precomputed W1 halves ----------------
__global__ __launch_bounds__(256, 2) void edge_kernel(
    const float* __restrict__ hsp, const float* __restrict__ hdp,
    const float* __restrict__ pos,
    const int* __restrict__ ssrc, const int* __restrict__ sdst,
    const float* __restrict__ ew1,
    const float* __restrict__ ew2, const float* __restrict__ eb2,
    const float* __restrict__ gw,  const float* __restrict__ gb,
    const float* __restrict__ pw1, const float* __restrict__ pb1,
    const float* __restrict__ pw2,
    float* __restrict__ agg, float* __restrict__ pos_acc,
    int E, int N)
{
    __shared__ float sW2[DH * DH];             // 16 KB
    __shared__ float sPW1[DH * DH];            // 16 KB
    __shared__ float sB2[DH], sPB1[DH], sGW[DH], sPW2[DH];

    const int ch = blockIdx.y;
    const int tid = threadIdx.x;

    {
        const float4* g2 = (const float4*)(ew2 + (size_t)ch * DH * DH);
        float4* l2 = (float4*)sW2;
        #pragma unroll
        for (int i = 0; i < 4; ++i) l2[tid + i * 256] = g2[tid + i * 256];
        const float4* g3 = (const float4*)(pw1 + (size_t)ch * DH * DH);
        float4* l3 = (float4*)sPW1;
        #pragma unroll
        for (int i = 0; i < 4; ++i) l3[tid + i * 256] = g3[tid + i * 256];
        if (tid < DH) {
            sB2[tid]  = eb2[(size_t)ch * DH + tid];
            sPB1[tid] = pb1[(size_t)ch * DH + tid];
            sGW[tid]  = gw[(size_t)ch * DH + tid];
            sPW2[tid] = pw2[(size_t)ch * DH + tid];
        }
    }
    __syncthreads();

    const int wl   = tid & 63;
    const int ck   = wl & 3;
    const int quad = wl >> 2;
    const int qedge = blockIdx.x * 256 + (tid >> 6) * 64 + quad * 4;

    f32x16 W128v;
    LOAD16(W128v, ew1 + (size_t)ch * (2 * DH + 1) * DH + (size_t)(2 * DH) * DH + ck * 16)

    const int4 s4 = *(const int4*)(ssrc + qedge);
    const int4 t4 = *(const int4*)(sdst + qedge);
    const int d_0 = t4.x, d_1 = t4.y, d_2 = t4.z, d_3 = t4.w;

    float rx0 = pos[3*s4.x+0]-pos[3*t4.x+0], ry0 = pos[3*s4.x+1]-pos[3*t4.x+1], rz0 = pos[3*s4.x+2]-pos[3*t4.x+2];
    float rx1 = pos[3*s4.y+0]-pos[3*t4.y+0], ry1 = pos[3*s4.y+1]-pos[3*t4.y+1], rz1 = pos[3*s4.y+2]-pos[3*t4.y+2];
    float rx2 = pos[3*s4.z+0]-pos[3*t4.z+0], ry2 = pos[3*s4.z+1]-pos[3*t4.z+1], rz2 = pos[3*s4.z+2]-pos[3*t4.z+2];
    float rx3 = pos[3*s4.w+0]-pos[3*t4.w+0], ry3 = pos[3*s4.w+1]-pos[3*t4.w+1], rz3 = pos[3*s4.w+2]-pos[3*t4.w+2];
    const float dd0 = rx0*rx0+ry0*ry0+rz0*rz0;
    const float dd1 = rx1*rx1+ry1*ry1+rz1*rz1;
    const float dd2 = rx2*rx2+ry2*ry2+rz2*rz2;
    const float dd3 = rx3*rx3+ry3*ry3+rz3*rz3;

    const float GB = gb[ch];
    const float* hsp_c = hsp + (size_t)ch * N * DH;
    const float* hdp_c = hdp + (size_t)ch * N * DH;

    // ---- m1 = silu(hsp[s] + hdp[t] + d2*w128) ----
    f32x16 A0, A1, A2, A3, T;
    LOAD16(A0, hsp_c + (size_t)s4.x * DH + ck*16)
    LOAD16(T,  hdp_c + (size_t)t4.x * DH + ck*16)  ADD16(A0, T)  FMAV(A0, W128v, dd0)
    LOAD16(A1, hsp_c + (size_t)s4.y * DH + ck*16)
    LOAD16(T,  hdp_c + (size_t)t4.y * DH + ck*16)  ADD16(A1, T)  FMAV(A1, W128v, dd1)
    LOAD16(A2, hsp_c + (size_t)s4.z * DH + ck*16)
    LOAD16(T,  hdp_c + (size_t)t4.z * DH + ck*16)  ADD16(A2, T)  FMAV(A2, W128v, dd2)
    LOAD16(A3, hsp_c + (size_t)s4.w * DH + ck*16)
    LOAD16(T,  hdp_c + (size_t)t4.w * DH + ck*16)  ADD16(A3, T)  FMAV(A3, W128v, dd3)
    SILU16(A0) SILU16(A1) SILU16(A2) SILU16(A3)

    // ---- m2 = silu(m1 @ W2 + B2) ----
    f32x16 B0v, B1v, B2v, B3v;
    { f32x16 bz; LOAD16(bz, sB2 + ck*16) B0v = bz; B1v = bz; B2v = bz; B3v = bz; }
    WBPHASE(sW2, 0, QB0, A0,A1,A2,A3, B0v,B1v,B2v,B3v)
    WBPHASE(sW2, 1, QB1, A0,A1,A2,A3, B0v,B1v,B2v,B3v)
    WBPHASE(sW2, 2, QB2, A0,A1,A2,A3, B0v,B1v,B2v,B3v)
    WBPHASE(sW2, 3, QB3, A0,A1,A2,A3, B0v,B1v,B2v,B3v)
    SILU16(B0v) SILU16(B1v) SILU16(B2v) SILU16(B3v)

    // ---- gate (quad reduce via DPP) ----
    {
        f32x16 GWv; LOAD16(GWv, sGW + ck*16)
        float g0 = 0.f, g1 = 0.f, g2 = 0.f, g3 = 0.f;
        DOTV(g0, B0v, GWv) DOTV(g1, B1v, GWv) DOTV(g2, B2v, GWv) DOTV(g3, B3v, GWv)
        g0 += QPERM(g0, QXOR1); g0 += QPERM(g0, QXOR2);
        g1 += QPERM(g1, QXOR1); g1 += QPERM(g1, QXOR2);
        g2 += QPERM(g2, QXOR1); g2 += QPERM(g2, QXOR2);
        g3 += QPERM(g3, QXOR1); g3 += QPERM(g3, QXOR2);
        const float ga0 = sigmoidf_(GB + g0), ga1 = sigmoidf_(GB + g1);
        const float ga2 = sigmoidf_(GB + g2), ga3 = sigmoidf_(GB + g3);
        MUL16(B0v, ga0) MUL16(B1v, ga1) MUL16(B2v, ga2) MUL16(B3v, ga3)
    }

    // ---- q = silu(m2 @ PW1 + PB1); p = q @ PW2 ----
    { f32x16 bz; LOAD16(bz, sPB1 + ck*16) A0 = bz; A1 = bz; A2 = bz; A3 = bz; }
    WBPHASE(sPW1, 0, QB0, B0v,B1v,B2v,B3v, A0,A1,A2,A3)
    WBPHASE(sPW1, 1, QB1, B0v,B1v,B2v,B3v, A0,A1,A2,A3)
    WBPHASE(sPW1, 2, QB2, B0v,B1v,B2v,B3v, A0,A1,A2,A3)
    WBPHASE(sPW1, 3, QB3, B0v,B1v,B2v,B3v, A0,A1,A2,A3)
    SILU16(A0) SILU16(A1) SILU16(A2) SILU16(A3)
    float p0 = 0.f, p1 = 0.f, p2 = 0.f, p3 = 0.f;
    {
        f32x16 PW2v; LOAD16(PW2v, sPW2 + ck*16)
        DOTV(p0, A0, PW2v) DOTV(p1, A1, PW2v) DOTV(p2, A2, PW2v) DOTV(p3, A3, PW2v)
        p0 += QPERM(p0, QXOR1); p0 += QPERM(p0, QXOR2);
        p1 += QPERM(p1, QXOR1); p1 += QPERM(p1, QXOR2);
        p2 += QPERM(p2, QXOR1); p2 += QPERM(p2, QXOR2);
        p3 += QPERM(p3, QXOR1); p3 += QPERM(p3, QXOR2);
    }
    float tx0 = fminf(fmaxf(rx0*p0, -2.f), 2.f), ty0 = fminf(fmaxf(ry0*p0, -2.f), 2.f), tz0 = fminf(fmaxf(rz0*p0, -2.f), 2.f);
    float tx1 = fminf(fmaxf(rx1*p1, -2.f), 2.f), ty1 = fminf(fmaxf(ry1*p1, -2.f), 2.f), tz1 = fminf(fmaxf(rz1*p1, -2.f), 2.f);
    float tx2 = fminf(fmaxf(rx2*p2, -2.f), 2.f), ty2 = fminf(fmaxf(ry2*p2, -2.f), 2.f), tz2 = fminf(fmaxf(rz2*p2, -2.f), 2.f);
    float tx3 = fminf(fmaxf(rx3*p3, -2.f), 2.f), ty3 = fminf(fmaxf(ry3*p3, -2.f), 2.f), tz3 = fminf(fmaxf(rz3*p3, -2.f), 2.f);

    // ---- in-lane suffix merge over my 4 sorted edges ----
    const float e01 = (d_0 == d_1) ? 1.f : 0.f;
    const float e12 = (d_1 == d_2) ? 1.f : 0.f;
    const float e23 = (d_2 == d_3) ? 1.f : 0.f;
    FMAV(B2v, B3v, e23) tx2 = fmaf(e23, tx3, tx2); ty2 = fmaf(e23, ty3, ty2); tz2 = fmaf(e23, tz3, tz2);
    FMAV(B1v, B2v, e12) tx1 = fmaf(e12, tx2, tx1); ty1 = fmaf(e12, ty2, ty1); tz1 = fmaf(e12, tz2, tz1);
    FMAV(B0v, B1v, e01) tx0 = fmaf(e01, tx1, tx0); ty0 = fmaf(e01, ty1, ty0); tz0 = fmaf(e01, tz1, tz0);
    const float full0 = e01 * e12 * e23;
    const float f1 = e12 * e23;
    const float f2 = e23;

    // ---- cross-quad chain scan ----
    f32x16 Pv = B0v;
    float ppx = tx0, ppy = ty0, ppz = tz0;
    float fullf = full0;
    int hk = d_0, tk = d_3;
    SCANSTEP(4) SCANSTEP(8) SCANSTEP(16) SCANSTEP(32)
    f32x16 Sv; SHFL16D(Sv, Pv, 4)
    float spx = __shfl_down(ppx, 4), spy = __shfl_down(ppy, 4), spz = __shfl_down(ppz, 4);
    const int g1hk = __shfl_down(d_0, 4);
    const float sf = (((wl + 4) < 64) && (d_3 == g1hk)) ? 1.f : 0.f;
    MUL16(Sv, sf) spx *= sf; spy *= sf; spz *= sf;

    const int pd = __shfl_up(d_3, 4);
    const bool h0 = (quad == 0) || (pd != d_0);
    const bool h1 = (e01 == 0.f);
    const bool h2 = (e12 == 0.f);
    const bool h3 = (e23 == 0.f);

#define FLUSH(COND, DJ, BV, F, TX, TY, TZ) \
    if (COND) { \
        float* ar = agg + ((size_t)ch * N + (DJ)) * DH + ck * 16; \
        atomicAdd(ar+0,  BV[0]+(F)*Sv[0]);   atomicAdd(ar+1,  BV[1]+(F)*Sv[1]); \
        atomicAdd(ar+2,  BV[2]+(F)*Sv[2]);   atomicAdd(ar+3,  BV[3]+(F)*Sv[3]); \
        atomicAdd(ar+4,  BV[4]+(F)*Sv[4]);   atomicAdd(ar+5,  BV[5]+(F)*Sv[5]); \
        atomicAdd(ar+6,  BV[6]+(F)*Sv[6]);   atomicAdd(ar+7,  BV[7]+(F)*Sv[7]); \
        atomicAdd(ar+8,  BV[8]+(F)*Sv[8]);   atomicAdd(ar+9,  BV[9]+(F)*Sv[9]); \
        atomicAdd(ar+10, BV[10]+(F)*Sv[10]); atomicAdd(ar+11, BV[11]+(F)*Sv[11]); \
        atomicAdd(ar+12, BV[12]+(F)*Sv[12]); atomicAdd(ar+13, BV[13]+(F)*Sv[13]); \
        atomicAdd(ar+14, BV[14]+(F)*Sv[14]); atomicAdd(ar+15, BV[15]+(F)*Sv[15]); \
        if (ck == 0) { \
            atomicAdd(&pos_acc[(DJ)*3+0], (TX)+(F)*spx); \
            atomicAdd(&pos_acc[(DJ)*3+1], (TY)+(F)*spy); \
            atomicAdd(&pos_acc[(DJ)*3+2], (TZ)+(F)*spz); } }

    FLUSH(h0, d_0, B0v, full0, tx0, ty0, tz0)
    FLUSH(h1, d_1, B1v, f1,    tx1, ty1, tz1)
    FLUSH(h2, d_2, B2v, f2,    tx2, ty2, tz2)
    FLUSH(h3, d_3, B3v, 1.0f,  tx3, ty3, tz3)
#undef FLUSH
}

// ---------------- fused_out: node update + mix_out for 8 nodes ----------------
__global__ __launch_bounds__(256) void fused_out_kernel(
        const float* __restrict__ h, const float* __restrict__ agg,
        const float* __restrict__ nw, const float* __restrict__ nb,
        const float* __restrict__ Wout,
        float* __restrict__ x, int N) {
    __shared__ float hl[8][CC * DH];   // 8 KB
    __shared__ float al[8][CC * DH];   // 8 KB
    __shared__ float ol[8][CC * DH];   // 8 KB
    const int i0 = blockIdx.x * 8;
    const int tid = threadIdx.x;
    const int c = tid >> 6, d = tid & 63;

    for (int t = tid; t < 8 * CC * DH; t += 256) {
        int j = t >> 8, cd = t & 255;
        int cc = cd >> 6, dd = cd & 63;
        int i = i0 + j;
        if (i < N) {
            hl[j][cd] = h[((size_t)cc * N + i) * DH + dd];
            al[j][cd] = agg[((size_t)cc * N + i) * DH + dd];
        } else {
            hl[j][cd] = 0.f;
            al[j][cd] = 0.f;
        }
    }
    __syncthreads();

    // node: ol[j][c*64+d] = nb + sum_k hl[j][c*64+k]*nw[c][k][d] + al[j][c*64+k]*nw[c][64+k][d]
    {
        const float* W = nw + (size_t)c * (2 * DH) * DH;
        const float bn = nb[(size_t)c * DH + d];
        float acc[8] = {bn, bn, bn, bn, bn, bn, bn, bn};
        #pragma unroll 4
        for (int k = 0; k < DH; ++k) {
            const float w_h = W[(size_t)k * DH + d];
            const float w_a = W[(size_t)(DH + k) * DH + d];
            #pragma unroll
            for (int j = 0; j < 8; ++j) {
                acc[j] += hl[j][c * DH + k] * w_h + al[j][c * DH + k] * w_a;
            }
        }
        #pragma unroll
        for (int j = 0; j < 8; ++j) ol[j][tid] = acc[j];
    }
    __syncthreads();

    // mix_out: x[i] += ol[i] @ Wout   (o = tid&127, g = tid>>7; 2 groups x 4 nodes)
    const int o = tid & 127, g = tid >> 7;
    float acc[4] = {0.f, 0.f, 0.f, 0.f};
    for (int cd = 0; cd < CC * DH; ++cd) {
        float w = Wout[(size_t)cd * DIN + o];
        #pragma unroll
        for (int j = 0; j < 4; ++j) acc[j] += ol[g * 4 + j][cd] * w;
    }
    #pragma unroll
    for (int j = 0; j < 4; ++j) {
        int i = i0 + g * 4 + j;
        if (i < N) x[(size_t)i * DIN + o] += acc[j];
    }
}

// ---------------- pos finalize ----------------
__global__ void pos_fin_kernel(float* __restrict__ pos, const float* __restrict__ pos_acc,
                               const int* __restrict__ cnt, int N) {
    int i = blockIdx.x * 256 + threadIdx.x;
    if (i < N) {
        float inv = 1.0f / ((float)CC * fmaxf((float)cnt[i], 1.0f));
        pos[i * 3 + 0] += pos_acc[i * 3 + 0] * inv;
        pos[i * 3 + 1] += pos_acc[i * 3 + 1] * inv;
        pos[i * 3 + 2] += pos_acc[i * 3 + 2] * inv;
    }
}

extern "C" void kernel_launch(void* const* d_in, const int* in_sizes, int n_in,
                              void* d_out, int out_size, void* d_ws, size_t ws_size,
                              hipStream_t stream) {
    const float* x         = (const float*)d_in[0];
    const float* pos       = (const float*)d_in[1];
    const int*   ei        = (const int*)d_in[2];
    const float* mix_in_w  = (const float*)d_in[3];
    const float* mix_out_w = (const float*)d_in[4];
    const float* ew1       = (const float*)d_in[5];
    const float* eb1       = (const float*)d_in[6];
    const float* ew2       = (const float*)d_in[7];
    const float* eb2       = (const float*)d_in[8];
    const float* gw        = (const float*)d_in[9];
    const float* gb        = (const float*)d_in[10];
    const float* nw        = (const float*)d_in[11];
    const float* nb        = (const float*)d_in[12];
    const float* pw1       = (const float*)d_in[13];
    const float* pb1       = (const float*)d_in[14];
    const float* pw2       = (const float*)d_in[15];

    const int* src = ei;
    const int* dst = ei + EE;

    float* xout    = (float*)d_out;
    float* pos_out = xout + (size_t)NN * DIN;

    float* hbuf    = (float*)d_ws;                     // C*N*64
    float* aggb    = hbuf + (size_t)CC * NN * DH;      // C*N*64
    float* hsp     = aggb + (size_t)CC * NN * DH;      // C*N*64
    float* hdp     = hsp  + (size_t)CC * NN * DH;      // C*N*64
    float* pos_cur = hdp  + (size_t)CC * NN * DH;      // N*3
    float* pos_acc = pos_cur + (size_t)NN * 3;         // N*3
    int*   cnt_i   = (int*)(pos_acc + (size_t)NN * 3); // N
    int*   offs    = cnt_i + NN;                       // N
    int*   fill    = offs + NN;                        // N
    int*   bsum    = fill + NN;                        // 256
    int*   ssrc    = bsum + 256;                       // E
    int*   sdst    = ssrc + EE;                        // E

    const int NB = (NN + 255) / 256;

    hipMemcpyAsync(xout, x, sizeof(float) * NN * DIN, hipMemcpyDeviceToDevice, stream);
    hipMemcpyAsync(pos_cur, pos, sizeof(float) * NN * 3, hipMemcpyDeviceToDevice, stream);
    hipMemsetAsync(cnt_i, 0, sizeof(int) * NN, stream);
    hipMemsetAsync(fill, 0, sizeof(int) * NN, stream);

    cnt_kernel<<<(EE + 255) / 256, 256, 0, stream>>>(dst, cnt_i, EE);
    scan1<<<NB, 256, 0, stream>>>(cnt_i, offs, bsum, NN);
    scan2<<<1, 256, 0, stream>>>(bsum, NB);
    scan3<<<NB, 256, 0, stream>>>(offs, bsum, NN);
    order_kernel<<<(EE + 255) / 256, 256, 0, stream>>>(src, dst, offs, fill, ssrc, sdst, EE);

    for (int l = 0; l < LL; ++l) {
        hipMemsetAsync(aggb, 0, sizeof(float) * CC * NN * DH, stream);
        hipMemsetAsync(pos_acc, 0, sizeof(float) * NN * 3, stream);

        fused_in_kernel<<<(NN + 7) / 8, 256, 0, stream>>>(
            xout, mix_in_w + (size_t)l * DIN * CC * DH,
            ew1 + (size_t)l * CC * (2 * DH + 1) * DH,
            eb1 + (size_t)l * CC * DH,
            hbuf, hsp, hdp, NN);

        edge_kernel<<<dim3(EE / 256, CC), 256, 0, stream>>>(
            hsp, hdp, pos_cur, ssrc, sdst,
            ew1 + (size_t)l * CC * (2 * DH + 1) * DH,
            ew2 + (size_t)l * CC * DH * DH,
            eb2 + (size_t)l * CC * DH,
            gw  + (size_t)l * CC * DH,
            gb  + (size_t)l * CC,
            pw1 + (size_t)l * CC * DH * DH,
            pb1 + (size_t)l * CC * DH,
            pw2 + (size_t)l * CC * DH,
            aggb, pos_acc, EE, NN);

        fused_out_kernel<<<(NN + 7) / 8, 256, 0, stream>>>(
            hbuf, aggb,
            nw + (size_t)l * CC * 2 * DH * DH,
            nb + (size_t)l * CC * DH,
            mix_out_w + (size_t)l * CC * DH * DIN,
            xout, NN);

        pos_fin_kernel<<<(NN + 255) / 256, 256, 0, stream>>>(pos_cur, pos_acc, cnt_i, NN);
    }

    hipMemcpyAsync(pos_out, pos_cur, sizeof(float) * NN * 3, hipMemcpyDeviceToDevice, stream);
}